// Round 9
// baseline (178.784 us; speedup 1.0000x reference)
//
#include <hip/hip_runtime.h>

#define B_ 4
#define C_ 64
#define IC_ 32
#define N_ 4096
#define LOG2E 1.44269504088896341f
#define AGENT_SCOPE __HIP_MEMORY_SCOPE_AGENT

typedef __attribute__((ext_vector_type(8))) short short8;
typedef __attribute__((ext_vector_type(4))) float floatx4;

__device__ __forceinline__ unsigned short f2bf(float f) {
  unsigned u = __float_as_uint(f);
  u += 0x7FFFu + ((u >> 16) & 1u);   // round-to-nearest-even
  return (unsigned short)(u >> 16);
}
__device__ __forceinline__ float bf2f(unsigned short h) {
  return __uint_as_float(((unsigned)h) << 16);
}

// grid-wide barrier: one arrival per block, t0 spins, agent-scope atomics carry
// the cross-XCD wb/inv. Counters zeroed by pack_xw_k earlier in the stream.
__device__ __forceinline__ void grid_barrier(unsigned* cnt, unsigned target) {
  __syncthreads();
  if (threadIdx.x == 0) {
    __hip_atomic_fetch_add(cnt, 1u, __ATOMIC_ACQ_REL, AGENT_SCOPE);
    while (__hip_atomic_load(cnt, __ATOMIC_ACQUIRE, AGENT_SCOPE) < target)
      __builtin_amdgcn_s_sleep(2);
  }
  __syncthreads();
}

// ---------------- pack: x -> padded cl bf16; weights; pad rings; barrier counters ----
__global__ void __launch_bounds__(256) pack_xw_k(
    const float* __restrict__ x, unsigned short* __restrict__ xclp,
    unsigned short* __restrict__ y1clp, unsigned short* __restrict__ y2clp,
    const float* __restrict__ d1_w, const float* __restrict__ d2_w, const float* __restrict__ d3_w,
    const float* __restrict__ th_w, const float* __restrict__ ph_w, const float* __restrict__ g_w,
    const float* __restrict__ th_b, const float* __restrict__ ph_b, const float* __restrict__ g_b,
    unsigned short* __restrict__ wpk, unsigned short* __restrict__ wproj, float* __restrict__ bproj,
    unsigned* __restrict__ bar)
{
  __shared__ float s[64][65];
  const int t = threadIdx.x;
  if (blockIdx.x < 256) {
    const int b = blockIdx.x >> 6, h = blockIdx.x & 63;
    for (int idx = t; idx < 4096; idx += 256) {
      int c = idx >> 6, w = idx & 63;
      s[c][w] = x[((size_t)(b * 64 + c)) * 4096 + h * 64 + w];
    }
    __syncthreads();
    for (int idx = t; idx < 4096; idx += 256) {
      int w = idx >> 6, c = idx & 63;
      xclp[(((size_t)b * 66 + h + 1) * 66 + (w + 1)) * 64 + c] = f2bf(s[c][w]);
    }
  } else {
    const int tid = (blockIdx.x - 256) * 256 + t;
    if (tid < 2) bar[tid] = 0;
    for (int idx = tid; idx < 3 * 36864; idx += 16 * 256) {
      int cv = idx / 36864, r = idx % 36864;
      int tap = r / 4096, r2 = r % 4096;
      int oc = r2 >> 6, ic = r2 & 63;
      const float* src = (cv == 0) ? d1_w : (cv == 1) ? d2_w : d3_w;
      wpk[(size_t)cv * 36864 + tap * 4096 + oc * 64 + ic] = f2bf(src[oc * 576 + ic * 9 + tap]);
    }
    for (int idx = tid; idx < 6144; idx += 16 * 256) {
      int m = idx >> 6, ic = idx & 63;
      float v = (m < 32) ? LOG2E * th_w[m * 64 + ic]
              : (m < 64) ? ph_w[(m - 32) * 64 + ic]
                         : g_w[(m - 64) * 64 + ic];
      wproj[m * 64 + ic] = f2bf(v);
    }
    for (int m = tid; m < 96; m += 16 * 256) {
      bproj[m] = (m < 32) ? LOG2E * th_b[m] : (m < 64) ? ph_b[m - 32] : g_b[m - 64];
    }
    // zero pad rings of the three padded conv buffers
#pragma unroll
    for (int img = 0; img < 3; ++img) {
      const int P = (img == 0) ? 66 : (img == 1) ? 34 : 18;
      unsigned short* dst = (img == 0) ? xclp : (img == 1) ? y1clp : y2clp;
      const int ring = 2 * P + 2 * (P - 2);
      const int tot = B_ * ring * 64;
      for (int idx = tid; idx < tot; idx += 16 * 256) {
        int c = idx & 63, r = idx >> 6;
        int k = r % ring, b = r / ring;
        int h, w;
        if (k < P)          { h = 0;     w = k; }
        else if (k < 2 * P) { h = P - 1; w = k - P; }
        else { int q = k - 2 * P; h = 1 + (q >> 1); w = (q & 1) ? (P - 1) : 0; }
        dst[(((size_t)b * P + h) * P + w) * 64 + c] = 0;
      }
    }
  }
}

// ---------------- implicit-GEMM conv 3x3 s2, 64->64 ch, MFMA bf16, 1 wave/block ------
template<int IN_PW, int OUT_H, bool LRELU, bool OUT_BF16>
__global__ void __launch_bounds__(64) convmf_k(
    const unsigned short* __restrict__ xin, const unsigned short* __restrict__ wp,
    const float* __restrict__ bias, unsigned short* __restrict__ obf,
    float* __restrict__ of32)
{
  constexpr int NTILES = OUT_H * OUT_H / 16;
  const int lane = threadIdx.x;
  const int n15 = lane & 15, quad = lane >> 4;
  int bx = blockIdx.x;
  const int octile = bx & 3; bx >>= 2;
  const int otile = bx % NTILES;
  const int b = bx / NTILES;
  const int o = otile * 16 + n15;
  const int oh = o / OUT_H, ow = o % OUT_H;
  const unsigned short* xb = xin + (size_t)b * IN_PW * IN_PW * 64;
  floatx4 acc = {0.f, 0.f, 0.f, 0.f};
#pragma unroll
  for (int tap = 0; tap < 9; ++tap) {
    const int kh = tap / 3, kw = tap % 3;
    const unsigned short* xpix = xb + ((size_t)(oh * 2 + kh) * IN_PW + (ow * 2 + kw)) * 64;
#pragma unroll
    for (int ks = 0; ks < 2; ++ks) {
      short8 af = *reinterpret_cast<const short8*>(
          wp + ((size_t)tap * 64 + octile * 16 + n15) * 64 + ks * 32 + quad * 8);
      short8 bf = *reinterpret_cast<const short8*>(xpix + ks * 32 + quad * 8);
      acc = __builtin_amdgcn_mfma_f32_16x16x32_bf16(af, bf, acc, 0, 0, 0);
    }
  }
  const float4 bv = *reinterpret_cast<const float4*>(bias + octile * 16 + quad * 4);
  float v[4] = {acc[0] + bv.x, acc[1] + bv.y, acc[2] + bv.z, acc[3] + bv.w};
  if (LRELU) {
#pragma unroll
    for (int r = 0; r < 4; ++r) v[r] = (v[r] >= 0.f) ? v[r] : 0.2f * v[r];
  }
  if (OUT_BF16) {
    constexpr int OPW = OUT_H + 2;
    unsigned short pk[4];
#pragma unroll
    for (int r = 0; r < 4; ++r) pk[r] = f2bf(v[r]);
    *reinterpret_cast<uint2*>(
        obf + (((size_t)b * OPW + oh + 1) * OPW + (ow + 1)) * 64 + octile * 16 + quad * 4) =
        *reinterpret_cast<uint2*>(pk);
  } else {
    *reinterpret_cast<float4*>(
        of32 + ((size_t)b * OUT_H * OUT_H + o) * 64 + octile * 16 + quad * 4) =
        *reinterpret_cast<float4*>(v);
  }
}

// ---------------- fused: bilinear upsample + sigmoid gate + 1x1 proj MFMA ------------
__global__ void __launch_bounds__(256) upsproj_k(
    const float* __restrict__ y3cl, const float* __restrict__ x,
    const unsigned short* __restrict__ wproj, const float* __restrict__ bproj,
    unsigned short* __restrict__ am_cl, unsigned short* __restrict__ thph,
    unsigned short* __restrict__ g16)
{
  const int b = blockIdx.x >> 6, oh = blockIdx.x & 63;
  const int t = threadIdx.x;
  __shared__ float s0[512], s1[512];
  __shared__ unsigned short s_am[64][72];
  float sh = (oh + 0.5f) * 0.125f - 0.5f;
  float fh = floorf(sh); float ah = sh - fh; int h0 = (int)fh;
  int h0c = min(7, max(0, h0)), h1c = min(7, max(0, h0 + 1));
  const float* yb = y3cl + (size_t)b * 4096;
  for (int i = t; i < 512; i += 256) { s0[i] = yb[h0c * 512 + i]; s1[i] = yb[h1c * 512 + i]; }
  __syncthreads();
  {
    const int ow = t >> 2, cq = t & 3;
    float sw = (ow + 0.5f) * 0.125f - 0.5f;
    float fw = floorf(sw); float aw = sw - fw; int w0 = (int)fw;
    int w0c = min(7, max(0, w0)), w1c = min(7, max(0, w0 + 1));
    const int n = oh * 64 + ow;
    const float* xb = x + (size_t)b * 64 * 4096 + n;
    unsigned short* ap = am_cl + ((size_t)b * N_ + n) * 64 + cq * 16;
#pragma unroll
    for (int u = 0; u < 4; ++u) {
      int c0 = cq * 16 + u * 4;
      float4 a00 = *reinterpret_cast<const float4*>(&s0[w0c * 64 + c0]);
      float4 a01 = *reinterpret_cast<const float4*>(&s0[w1c * 64 + c0]);
      float4 a10 = *reinterpret_cast<const float4*>(&s1[w0c * 64 + c0]);
      float4 a11 = *reinterpret_cast<const float4*>(&s1[w1c * 64 + c0]);
      float i0[4] = {a00.x * (1.f - aw) + a01.x * aw, a00.y * (1.f - aw) + a01.y * aw,
                     a00.z * (1.f - aw) + a01.z * aw, a00.w * (1.f - aw) + a01.w * aw};
      float i1[4] = {a10.x * (1.f - aw) + a11.x * aw, a10.y * (1.f - aw) + a11.y * aw,
                     a10.z * (1.f - aw) + a11.z * aw, a10.w * (1.f - aw) + a11.w * aw};
      unsigned short pk[4];
#pragma unroll
      for (int vi = 0; vi < 4; ++vi) {
        float vv = i0[vi] * (1.f - ah) + i1[vi] * ah;
        float xv = xb[(size_t)(c0 + vi) * 4096];
        float sig = 1.f / (1.f + __expf(-vv));
        pk[vi] = f2bf(sig * xv);
      }
      uint2 pkt = *reinterpret_cast<uint2*>(pk);
      *reinterpret_cast<uint2*>(ap + u * 4) = pkt;
      *reinterpret_cast<uint2*>(&s_am[ow][c0]) = pkt;
    }
  }
  __syncthreads();
  const int wave = t >> 6, lane = t & 63;
  const int n15 = lane & 15, quad = lane >> 4;
  const int n = oh * 64 + wave * 16 + n15;
  const unsigned short* srow = &s_am[wave * 16 + n15][0];
  const short8 bf0 = *reinterpret_cast<const short8*>(srow + quad * 8);
  const short8 bf1 = *reinterpret_cast<const short8*>(srow + 32 + quad * 8);
#pragma unroll
  for (int mt = 0; mt < 6; ++mt) {
    short8 a0 = *reinterpret_cast<const short8*>(wproj + ((size_t)mt * 16 + n15) * 64 + quad * 8);
    short8 a1 = *reinterpret_cast<const short8*>(wproj + ((size_t)mt * 16 + n15) * 64 + 32 + quad * 8);
    floatx4 acc = {0.f, 0.f, 0.f, 0.f};
    acc = __builtin_amdgcn_mfma_f32_16x16x32_bf16(a0, bf0, acc, 0, 0, 0);
    acc = __builtin_amdgcn_mfma_f32_16x16x32_bf16(a1, bf1, acc, 0, 0, 0);
    const float4 bv = *reinterpret_cast<const float4*>(bproj + mt * 16 + quad * 4);
    float v[4] = {acc[0] + bv.x, acc[1] + bv.y, acc[2] + bv.z, acc[3] + bv.w};
    if (mt < 4) {
      unsigned short pk[4];
#pragma unroll
      for (int r = 0; r < 4; ++r) pk[r] = f2bf(v[r]);
      *reinterpret_cast<uint2*>(thph + ((size_t)b * N_ + n) * 64 + mt * 16 + quad * 4) =
          *reinterpret_cast<uint2*>(pk);
    } else {
#pragma unroll
      for (int r = 0; r < 4; ++r)
        g16[((size_t)b * 32 + (mt - 4) * 16 + quad * 4 + r) * N_ + n] = f2bf(v[r]);
    }
  }
}

// ---------------- mega attention: stats + scale_g + pv, 2 grid barriers --------------
#define TH_PITCH 40
#define PHI_PITCH 40
#define G_PITCH   136
union MegaLds {
  unsigned short th[256 * TH_PITCH];                 // phase A (20 KB)
  struct {
    unsigned short phi[2][128 * PHI_PITCH];          // phase C (20 KB)
    unsigned short g[2][32 * G_PITCH];               // phase C (17.4 KB)
  } c;
};

__global__ void __launch_bounds__(1024) attn_mega_k(
    const unsigned short* __restrict__ thph, unsigned short* g16,
    float* lpart, unsigned short* __restrict__ y2p, unsigned* bar)
{
  __shared__ MegaLds L;
  const int bid = blockIdx.x;
  const int t = threadIdx.x, wave = t >> 6, lane = t & 63;
  const int n15 = lane & 15, quad = lane >> 4;

  // ================= phase A: stats (partial l over i-slice) =================
  {
    const int b = bid & 3, iz = (bid >> 2) & 15, jq = bid >> 6;
    const unsigned short* base = thph + (size_t)b * N_ * 64;
    {
      const int row = t >> 2, ck = t & 3;
      *reinterpret_cast<uint4*>(&L.th[row * TH_PITCH + ck * 8]) =
          *reinterpret_cast<const uint4*>(base + (size_t)(iz * 256 + row) * 64 + ck * 8);
    }
    const int jw = jq * 1024 + wave * 64;
    short8 bv[4];
#pragma unroll
    for (int v = 0; v < 4; ++v)
      bv[v] = *reinterpret_cast<const short8*>(base + (size_t)(jw + v * 16 + n15) * 64 + 32 + quad * 8);
    __syncthreads();
    float ls[4] = {0.f, 0.f, 0.f, 0.f};
    short8 ac = *reinterpret_cast<const short8*>(&L.th[n15 * TH_PITCH + quad * 8]);
    for (int st = 0; st < 16; ++st) {
      const int rn = ((st < 15) ? st + 1 : st) * 16 + n15;
      short8 an = *reinterpret_cast<const short8*>(&L.th[rn * TH_PITCH + quad * 8]);
#pragma unroll
      for (int v = 0; v < 4; ++v) {
        floatx4 z = {0.f, 0.f, 0.f, 0.f};
        z = __builtin_amdgcn_mfma_f32_16x16x32_bf16(ac, bv[v], z, 0, 0, 0);
        ls[v] += (__builtin_amdgcn_exp2f(z[0]) + __builtin_amdgcn_exp2f(z[1]))
               + (__builtin_amdgcn_exp2f(z[2]) + __builtin_amdgcn_exp2f(z[3]));
      }
      ac = an;
    }
#pragma unroll
    for (int v = 0; v < 4; ++v) {
      ls[v] += __shfl_xor(ls[v], 16);
      ls[v] += __shfl_xor(ls[v], 32);
    }
    if (quad == 0) {
#pragma unroll
      for (int v = 0; v < 4; ++v)
        lpart[((size_t)iz * B_ + b) * N_ + jw + v * 16 + n15] = ls[v];
    }
  }
  grid_barrier(&bar[0], 256);

  // ================= phase B: fold 1/l into g =================
  {
    const int b = bid & 3;
    const int j = (bid >> 2) * 64 + (t & 63);
    const int cg = t >> 6;                 // 16 groups x 2 channels
    float l = 0.f;
#pragma unroll
    for (int iz = 0; iz < 16; ++iz) l += lpart[((size_t)iz * B_ + b) * N_ + j];
    const float rl = 1.f / l;
    unsigned short* gp = g16 + ((size_t)b * 32 + cg * 2) * N_ + j;
    gp[0]  = f2bf(bf2f(gp[0]) * rl);
    gp[N_] = f2bf(bf2f(gp[N_]) * rl);
  }
  grid_barrier(&bar[1], 256);

  // ================= phase C: pv (LDS-staged, custom k<->j pairing) =================
  {
    const int b = bid & 3, jq = (bid >> 2) & 3, ig = bid >> 4;
    const unsigned short* base = thph + (size_t)b * N_ * 64;
    const unsigned short* gs   = g16  + (size_t)b * 32 * N_;
    const int iw = ig * 256 + wave * 16;
    const short8 bth = *reinterpret_cast<const short8*>(base + (size_t)(iw + n15) * 64 + quad * 8);
    floatx4 Y0 = {0.f, 0.f, 0.f, 0.f}, Y1 = {0.f, 0.f, 0.f, 0.f};

    const bool isphi = t < 512;
    const int pr = (t & 511) >> 2, pseg = t & 3;     // phi row / 16B seg
    const int gc = (t & 511) >> 4, gseg = t & 15;    // g channel / 16B seg
    const int jbase = jq * 1024;

    uint4 s;
    if (isphi) s = *reinterpret_cast<const uint4*>(base + (size_t)(jbase + pr) * 64 + 32 + pseg * 8);
    else       s = *reinterpret_cast<const uint4*>(gs + (size_t)gc * N_ + jbase + gseg * 8);
    if (isphi) *reinterpret_cast<uint4*>(&L.c.phi[0][pr * PHI_PITCH + pseg * 8]) = s;
    else       *reinterpret_cast<uint4*>(&L.c.g[0][gc * G_PITCH + gseg * 8]) = s;
    __syncthreads();

    int j0 = jbase;
    for (int ch = 0; ch < 8; ++ch, j0 += 128) {
      const int cur = ch & 1;
      if (ch < 7) {
        const int jn = j0 + 128;
        if (isphi) s = *reinterpret_cast<const uint4*>(base + (size_t)(jn + pr) * 64 + 32 + pseg * 8);
        else       s = *reinterpret_cast<const uint4*>(gs + (size_t)gc * N_ + jn + gseg * 8);
      }
      const unsigned short* phb = &L.c.phi[cur][0];
      const unsigned short* glb = &L.c.g[cur][0];
      unsigned pk[8][2];
#pragma unroll
      for (int jt = 0; jt < 8; ++jt) {
        short8 aph = *reinterpret_cast<const short8*>(phb + (jt * 16 + n15) * PHI_PITCH + quad * 8);
        floatx4 z = {0.f, 0.f, 0.f, 0.f};
        z = __builtin_amdgcn_mfma_f32_16x16x32_bf16(aph, bth, z, 0, 0, 0);
        float e0 = __builtin_amdgcn_exp2f(z[0]), e1 = __builtin_amdgcn_exp2f(z[1]);
        float e2 = __builtin_amdgcn_exp2f(z[2]), e3 = __builtin_amdgcn_exp2f(z[3]);
        pk[jt][0] = __builtin_amdgcn_perm(__float_as_uint(e1), __float_as_uint(e0), 0x07060302);
        pk[jt][1] = __builtin_amdgcn_perm(__float_as_uint(e3), __float_as_uint(e2), 0x07060302);
      }
#pragma unroll
      for (int sg = 0; sg < 4; ++sg) {
        union { unsigned u[4]; short8 v; } pa, gb0, gb1;
        pa.u[0] = pk[2 * sg][0];     pa.u[1] = pk[2 * sg][1];
        pa.u[2] = pk[2 * sg + 1][0]; pa.u[3] = pk[2 * sg + 1][1];
        const unsigned short* gr0 = glb + n15 * G_PITCH + sg * 32 + quad * 4;
        const unsigned short* gr1 = glb + (16 + n15) * G_PITCH + sg * 32 + quad * 4;
        uint2 lo0 = *reinterpret_cast<const uint2*>(gr0);
        uint2 hi0 = *reinterpret_cast<const uint2*>(gr0 + 16);
        uint2 lo1 = *reinterpret_cast<const uint2*>(gr1);
        uint2 hi1 = *reinterpret_cast<const uint2*>(gr1 + 16);
        gb0.u[0] = lo0.x; gb0.u[1] = lo0.y; gb0.u[2] = hi0.x; gb0.u[3] = hi0.y;
        gb1.u[0] = lo1.x; gb1.u[1] = lo1.y; gb1.u[2] = hi1.x; gb1.u[3] = hi1.y;
        Y0 = __builtin_amdgcn_mfma_f32_16x16x32_bf16(pa.v, gb0.v, Y0, 0, 0, 0);
        Y1 = __builtin_amdgcn_mfma_f32_16x16x32_bf16(pa.v, gb1.v, Y1, 0, 0, 0);
      }
      if (ch < 7) {
        const int nb = cur ^ 1;
        if (isphi) *reinterpret_cast<uint4*>(&L.c.phi[nb][pr * PHI_PITCH + pseg * 8]) = s;
        else       *reinterpret_cast<uint4*>(&L.c.g[nb][gc * G_PITCH + gseg * 8]) = s;
      }
      __syncthreads();
    }
    unsigned w0[2], w1[2];
    w0[0] = ((unsigned)f2bf(Y0[1]) << 16) | f2bf(Y0[0]);
    w0[1] = ((unsigned)f2bf(Y0[3]) << 16) | f2bf(Y0[2]);
    w1[0] = ((unsigned)f2bf(Y1[1]) << 16) | f2bf(Y1[0]);
    w1[1] = ((unsigned)f2bf(Y1[3]) << 16) | f2bf(Y1[2]);
    *reinterpret_cast<uint2*>(
        y2p + (((size_t)jq * B_ + b) * 32 + n15) * N_ + iw + quad * 4) =
        *reinterpret_cast<uint2*>(w0);
    *reinterpret_cast<uint2*>(
        y2p + (((size_t)jq * B_ + b) * 32 + 16 + n15) * N_ + iw + quad * 4) =
        *reinterpret_cast<uint2*>(w1);
  }
}

// ---------------- final: out = (W_y(y2) + am) * x ----------------
__global__ void __launch_bounds__(256) final_k(
    const unsigned short* __restrict__ y2p, const float* __restrict__ w_w,
    const float* __restrict__ w_b, const unsigned short* __restrict__ am_cl,
    const float* __restrict__ x, float* __restrict__ out)
{
  const int n0 = (blockIdx.x * 256 + threadIdx.x) * 2;
  const int o0 = blockIdx.y * 8;
  const int b  = blockIdx.z;
  float a0[8], a1[8];
#pragma unroll
  for (int u = 0; u < 8; ++u) { a0[u] = w_b[o0 + u]; a1[u] = a0[u]; }
  for (int c = 0; c < 32; ++c) {
    float s0 = 0.f, s1 = 0.f;
#pragma unroll
    for (int ph = 0; ph < 4; ++ph) {
      unsigned v = *reinterpret_cast<const unsigned*>(
          y2p + (((size_t)ph * B_ + b) * 32 + c) * N_ + n0);
      s0 += bf2f((unsigned short)(v & 0xffffu));
      s1 += bf2f((unsigned short)(v >> 16));
    }
#pragma unroll
    for (int u = 0; u < 8; ++u) {
      float wv = w_w[(o0 + u) * 32 + c];
      a0[u] += wv * s0; a1[u] += wv * s1;
    }
  }
  const short8 am0 = *reinterpret_cast<const short8*>(am_cl + ((size_t)b * N_ + n0) * 64 + o0);
  const short8 am1 = *reinterpret_cast<const short8*>(am_cl + ((size_t)b * N_ + n0 + 1) * 64 + o0);
#pragma unroll
  for (int u = 0; u < 8; ++u) {
    size_t off = ((size_t)b * 64 + o0 + u) * N_ + n0;
    float2 xv = *reinterpret_cast<const float2*>(x + off);
    float2 ov;
    ov.x = (a0[u] + bf2f((unsigned short)am0[u])) * xv.x;
    ov.y = (a1[u] + bf2f((unsigned short)am1[u])) * xv.y;
    *reinterpret_cast<float2*>(out + off) = ov;
  }
}

extern "C" void kernel_launch(void* const* d_in, const int* in_sizes, int n_in,
                              void* d_out, int out_size, void* d_ws, size_t ws_size,
                              hipStream_t stream) {
  const float* x    = (const float*)d_in[0];
  const float* d1_w = (const float*)d_in[1];
  const float* d1_b = (const float*)d_in[2];
  const float* d2_w = (const float*)d_in[3];
  const float* d2_b = (const float*)d_in[4];
  const float* d3_w = (const float*)d_in[5];
  const float* d3_b = (const float*)d_in[6];
  const float* g_w  = (const float*)d_in[7];
  const float* g_b  = (const float*)d_in[8];
  const float* th_w = (const float*)d_in[9];
  const float* th_b = (const float*)d_in[10];
  const float* ph_w = (const float*)d_in[11];
  const float* ph_b = (const float*)d_in[12];
  const float* w_w  = (const float*)d_in[13];
  const float* w_b  = (const float*)d_in[14];
  float* out = (float*)d_out;

  char* p = (char*)d_ws;
  unsigned short* am_cl = (unsigned short*)p;  p += (size_t)B_ * N_ * 64 * 2;        // 2 MB
  unsigned short* thph  = (unsigned short*)p;  p += (size_t)B_ * N_ * 64 * 2;        // 2 MB
  unsigned short* g16   = (unsigned short*)p;  p += (size_t)B_ * 32 * N_ * 2;        // 1 MB
  float* lpart          = (float*)p;           p += (size_t)16 * B_ * N_ * 4;        // 1 MB
  unsigned short* y2p   = (unsigned short*)p;  p += (size_t)4 * B_ * 32 * N_ * 2;    // 4 MB
  float* y3cl           = (float*)p;           p += (size_t)B_ * 64 * 64 * 4;        // 64 KB
  unsigned short* wpk   = (unsigned short*)p;  p += (size_t)3 * 36864 * 2;
  unsigned short* wproj = (unsigned short*)p;  p += (size_t)96 * 64 * 2;
  float* bproj          = (float*)p;           p += (size_t)96 * 4;
  unsigned* bar         = (unsigned*)p;        p += 256;                              // 2 counters
  unsigned short* xclp  = (unsigned short*)p;  p += (size_t)B_ * 66 * 66 * 64 * 2;
  unsigned short* y1clp = (unsigned short*)p;  p += (size_t)B_ * 34 * 34 * 64 * 2;
  unsigned short* y2clp = (unsigned short*)p;  p += (size_t)B_ * 18 * 18 * 64 * 2;

  pack_xw_k<<<272, 256, 0, stream>>>(x, xclp, y1clp, y2clp,
                                     d1_w, d2_w, d3_w, th_w, ph_w, g_w,
                                     th_b, ph_b, g_b, wpk, wproj, bproj, bar);
  convmf_k<66, 32, true,  true ><<<1024, 64, 0, stream>>>(xclp,  wpk,             d1_b, y1clp, nullptr);
  convmf_k<34, 16, true,  true ><<<256,  64, 0, stream>>>(y1clp, wpk + 36864,     d2_b, y2clp, nullptr);
  convmf_k<18,  8, false, false><<<64,   64, 0, stream>>>(y2clp, wpk + 2 * 36864, d3_b, nullptr, y3cl);
  upsproj_k<<<256, 256, 0, stream>>>(y3cl, x, wproj, bproj, am_cl, thph, g16);
  attn_mega_k<<<256, 1024, 0, stream>>>(thph, g16, lpart, y2p, bar);
  final_k<<<dim3(8, 8, 4), 256, 0, stream>>>(y2p, w_w, w_b, am_cl, x, out);
}

// Round 10
// 160.107 us; speedup vs baseline: 1.1167x; 1.1167x over previous
//
#include <hip/hip_runtime.h>

#define B_ 4
#define C_ 64
#define IC_ 32
#define N_ 4096
#define LOG2E 1.44269504088896341f

typedef __attribute__((ext_vector_type(8))) short short8;
typedef __attribute__((ext_vector_type(4))) float floatx4;

__device__ __forceinline__ unsigned short f2bf(float f) {
  unsigned u = __float_as_uint(f);
  u += 0x7FFFu + ((u >> 16) & 1u);   // round-to-nearest-even
  return (unsigned short)(u >> 16);
}
__device__ __forceinline__ float bf2f(unsigned short h) {
  return __uint_as_float(((unsigned)h) << 16);
}

// ---------------- pack: x -> padded cl bf16; weights; conv pad rings ----------------
__global__ void __launch_bounds__(256) pack_xw_k(
    const float* __restrict__ x, unsigned short* __restrict__ xclp,
    unsigned short* __restrict__ y1clp, unsigned short* __restrict__ y2clp,
    const float* __restrict__ d1_w, const float* __restrict__ d2_w, const float* __restrict__ d3_w,
    const float* __restrict__ th_w, const float* __restrict__ ph_w, const float* __restrict__ g_w,
    const float* __restrict__ th_b, const float* __restrict__ ph_b, const float* __restrict__ g_b,
    unsigned short* __restrict__ wpk, unsigned short* __restrict__ wproj, float* __restrict__ bproj)
{
  __shared__ float s[64][65];
  const int t = threadIdx.x;
  if (blockIdx.x < 256) {
    const int b = blockIdx.x >> 6, h = blockIdx.x & 63;
    for (int idx = t; idx < 4096; idx += 256) {
      int c = idx >> 6, w = idx & 63;
      s[c][w] = x[((size_t)(b * 64 + c)) * 4096 + h * 64 + w];
    }
    __syncthreads();
    for (int idx = t; idx < 4096; idx += 256) {
      int w = idx >> 6, c = idx & 63;
      xclp[(((size_t)b * 66 + h + 1) * 66 + (w + 1)) * 64 + c] = f2bf(s[c][w]);
    }
  } else {
    const int tid = (blockIdx.x - 256) * 256 + t;
    for (int idx = tid; idx < 3 * 36864; idx += 16 * 256) {
      int cv = idx / 36864, r = idx % 36864;
      int tap = r / 4096, r2 = r % 4096;
      int oc = r2 >> 6, ic = r2 & 63;
      const float* src = (cv == 0) ? d1_w : (cv == 1) ? d2_w : d3_w;
      wpk[(size_t)cv * 36864 + tap * 4096 + oc * 64 + ic] = f2bf(src[oc * 576 + ic * 9 + tap]);
    }
    for (int idx = tid; idx < 6144; idx += 16 * 256) {
      int m = idx >> 6, ic = idx & 63;
      float v = (m < 32) ? LOG2E * th_w[m * 64 + ic]
              : (m < 64) ? ph_w[(m - 32) * 64 + ic]
                         : g_w[(m - 64) * 64 + ic];
      wproj[m * 64 + ic] = f2bf(v);
    }
    for (int m = tid; m < 96; m += 16 * 256) {
      bproj[m] = (m < 32) ? LOG2E * th_b[m] : (m < 64) ? ph_b[m - 32] : g_b[m - 64];
    }
    // zero pad rings of the three padded conv buffers
#pragma unroll
    for (int img = 0; img < 3; ++img) {
      const int P = (img == 0) ? 66 : (img == 1) ? 34 : 18;
      unsigned short* dst = (img == 0) ? xclp : (img == 1) ? y1clp : y2clp;
      const int ring = 2 * P + 2 * (P - 2);
      const int tot = B_ * ring * 64;
      for (int idx = tid; idx < tot; idx += 16 * 256) {
        int c = idx & 63, r = idx >> 6;
        int k = r % ring, b = r / ring;
        int h, w;
        if (k < P)          { h = 0;     w = k; }
        else if (k < 2 * P) { h = P - 1; w = k - P; }
        else { int q = k - 2 * P; h = 1 + (q >> 1); w = (q & 1) ? (P - 1) : 0; }
        dst[(((size_t)b * P + h) * P + w) * 64 + c] = 0;
      }
    }
  }
}

// ---------------- implicit-GEMM conv 3x3 s2, 64->64 ch, MFMA bf16, 1 wave/block ------
template<int IN_PW, int OUT_H, bool LRELU, bool OUT_BF16>
__global__ void __launch_bounds__(64) convmf_k(
    const unsigned short* __restrict__ xin, const unsigned short* __restrict__ wp,
    const float* __restrict__ bias, unsigned short* __restrict__ obf,
    float* __restrict__ of32)
{
  constexpr int NTILES = OUT_H * OUT_H / 16;
  const int lane = threadIdx.x;
  const int n15 = lane & 15, quad = lane >> 4;
  int bx = blockIdx.x;
  const int octile = bx & 3; bx >>= 2;
  const int otile = bx % NTILES;
  const int b = bx / NTILES;
  const int o = otile * 16 + n15;
  const int oh = o / OUT_H, ow = o % OUT_H;
  const unsigned short* xb = xin + (size_t)b * IN_PW * IN_PW * 64;
  floatx4 acc = {0.f, 0.f, 0.f, 0.f};
#pragma unroll
  for (int tap = 0; tap < 9; ++tap) {
    const int kh = tap / 3, kw = tap % 3;
    const unsigned short* xpix = xb + ((size_t)(oh * 2 + kh) * IN_PW + (ow * 2 + kw)) * 64;
#pragma unroll
    for (int ks = 0; ks < 2; ++ks) {
      short8 af = *reinterpret_cast<const short8*>(
          wp + ((size_t)tap * 64 + octile * 16 + n15) * 64 + ks * 32 + quad * 8);
      short8 bf = *reinterpret_cast<const short8*>(xpix + ks * 32 + quad * 8);
      acc = __builtin_amdgcn_mfma_f32_16x16x32_bf16(af, bf, acc, 0, 0, 0);
    }
  }
  const float4 bv = *reinterpret_cast<const float4*>(bias + octile * 16 + quad * 4);
  float v[4] = {acc[0] + bv.x, acc[1] + bv.y, acc[2] + bv.z, acc[3] + bv.w};
  if (LRELU) {
#pragma unroll
    for (int r = 0; r < 4; ++r) v[r] = (v[r] >= 0.f) ? v[r] : 0.2f * v[r];
  }
  if (OUT_BF16) {
    constexpr int OPW = OUT_H + 2;
    unsigned short pk[4];
#pragma unroll
    for (int r = 0; r < 4; ++r) pk[r] = f2bf(v[r]);
    *reinterpret_cast<uint2*>(
        obf + (((size_t)b * OPW + oh + 1) * OPW + (ow + 1)) * 64 + octile * 16 + quad * 4) =
        *reinterpret_cast<uint2*>(pk);
  } else {
    *reinterpret_cast<float4*>(
        of32 + ((size_t)b * OUT_H * OUT_H + o) * 64 + octile * 16 + quad * 4) =
        *reinterpret_cast<float4*>(v);
  }
}

// ---------------- fused: bilinear upsample + sigmoid gate + 1x1 proj MFMA ------------
__global__ void __launch_bounds__(256) upsproj_k(
    const float* __restrict__ y3cl, const float* __restrict__ x,
    const unsigned short* __restrict__ wproj, const float* __restrict__ bproj,
    unsigned short* __restrict__ am_cl, unsigned short* __restrict__ thph,
    unsigned short* __restrict__ g16)
{
  const int b = blockIdx.x >> 6, oh = blockIdx.x & 63;
  const int t = threadIdx.x;
  __shared__ float s0[512], s1[512];
  __shared__ unsigned short s_am[64][72];
  float sh = (oh + 0.5f) * 0.125f - 0.5f;
  float fh = floorf(sh); float ah = sh - fh; int h0 = (int)fh;
  int h0c = min(7, max(0, h0)), h1c = min(7, max(0, h0 + 1));
  const float* yb = y3cl + (size_t)b * 4096;
  for (int i = t; i < 512; i += 256) { s0[i] = yb[h0c * 512 + i]; s1[i] = yb[h1c * 512 + i]; }
  __syncthreads();
  {
    const int ow = t >> 2, cq = t & 3;
    float sw = (ow + 0.5f) * 0.125f - 0.5f;
    float fw = floorf(sw); float aw = sw - fw; int w0 = (int)fw;
    int w0c = min(7, max(0, w0)), w1c = min(7, max(0, w0 + 1));
    const int n = oh * 64 + ow;
    const float* xb = x + (size_t)b * 64 * 4096 + n;
    unsigned short* ap = am_cl + ((size_t)b * N_ + n) * 64 + cq * 16;
#pragma unroll
    for (int u = 0; u < 4; ++u) {
      int c0 = cq * 16 + u * 4;
      float4 a00 = *reinterpret_cast<const float4*>(&s0[w0c * 64 + c0]);
      float4 a01 = *reinterpret_cast<const float4*>(&s0[w1c * 64 + c0]);
      float4 a10 = *reinterpret_cast<const float4*>(&s1[w0c * 64 + c0]);
      float4 a11 = *reinterpret_cast<const float4*>(&s1[w1c * 64 + c0]);
      float i0[4] = {a00.x * (1.f - aw) + a01.x * aw, a00.y * (1.f - aw) + a01.y * aw,
                     a00.z * (1.f - aw) + a01.z * aw, a00.w * (1.f - aw) + a01.w * aw};
      float i1[4] = {a10.x * (1.f - aw) + a11.x * aw, a10.y * (1.f - aw) + a11.y * aw,
                     a10.z * (1.f - aw) + a11.z * aw, a10.w * (1.f - aw) + a11.w * aw};
      unsigned short pk[4];
#pragma unroll
      for (int vi = 0; vi < 4; ++vi) {
        float vv = i0[vi] * (1.f - ah) + i1[vi] * ah;
        float xv = xb[(size_t)(c0 + vi) * 4096];
        float sig = 1.f / (1.f + __expf(-vv));
        pk[vi] = f2bf(sig * xv);
      }
      uint2 pkt = *reinterpret_cast<uint2*>(pk);
      *reinterpret_cast<uint2*>(ap + u * 4) = pkt;
      *reinterpret_cast<uint2*>(&s_am[ow][c0]) = pkt;
    }
  }
  __syncthreads();
  const int wave = t >> 6, lane = t & 63;
  const int n15 = lane & 15, quad = lane >> 4;
  const int n = oh * 64 + wave * 16 + n15;
  const unsigned short* srow = &s_am[wave * 16 + n15][0];
  const short8 bf0 = *reinterpret_cast<const short8*>(srow + quad * 8);
  const short8 bf1 = *reinterpret_cast<const short8*>(srow + 32 + quad * 8);
#pragma unroll
  for (int mt = 0; mt < 6; ++mt) {
    short8 a0 = *reinterpret_cast<const short8*>(wproj + ((size_t)mt * 16 + n15) * 64 + quad * 8);
    short8 a1 = *reinterpret_cast<const short8*>(wproj + ((size_t)mt * 16 + n15) * 64 + 32 + quad * 8);
    floatx4 acc = {0.f, 0.f, 0.f, 0.f};
    acc = __builtin_amdgcn_mfma_f32_16x16x32_bf16(a0, bf0, acc, 0, 0, 0);
    acc = __builtin_amdgcn_mfma_f32_16x16x32_bf16(a1, bf1, acc, 0, 0, 0);
    const float4 bv = *reinterpret_cast<const float4*>(bproj + mt * 16 + quad * 4);
    float v[4] = {acc[0] + bv.x, acc[1] + bv.y, acc[2] + bv.z, acc[3] + bv.w};
    if (mt < 4) {
      unsigned short pk[4];
#pragma unroll
      for (int r = 0; r < 4; ++r) pk[r] = f2bf(v[r]);
      *reinterpret_cast<uint2*>(thph + ((size_t)b * N_ + n) * 64 + mt * 16 + quad * 4) =
          *reinterpret_cast<uint2*>(pk);
    } else {
#pragma unroll
      for (int r = 0; r < 4; ++r)
        g16[((size_t)b * 32 + (mt - 4) * 16 + quad * 4 + r) * N_ + n] = f2bf(v[r]);
    }
  }
}

// ---------------- pass A: l_j = sum_i exp2(S'_ij), partials over 16 i-slices ---------
// 1D grid 1024, XCD swizzle: blocks sharing (b,iz) keep bid%8 fixed -> same XCD L2.
__global__ void __launch_bounds__(256) attn_stats_k(
    const unsigned short* __restrict__ thph, float* __restrict__ lpart)
{
  const int bid = blockIdx.x;
  const int b  = bid & 3;
  const int iz = (bid >> 2) & 15;
  const int jgrp = bid >> 6;
  const int t = threadIdx.x, wave = t >> 6, lane = t & 63;
  const int n15 = lane & 15, quad = lane >> 4;
  const int jw = jgrp * 256 + wave * 64;
  const unsigned short* base = thph + (size_t)b * N_ * 64;
  short8 bv[4];
#pragma unroll
  for (int v = 0; v < 4; ++v)
    bv[v] = *reinterpret_cast<const short8*>(base + (size_t)(jw + v * 16 + n15) * 64 + 32 + quad * 8);
  float ls[4] = {0.f, 0.f, 0.f, 0.f};
  const unsigned short* ap = base + (size_t)(iz * 256 + n15) * 64 + quad * 8;
  short8 ac = *reinterpret_cast<const short8*>(ap);
  for (int st = 0; st < 16; ++st) {
    short8 an = *reinterpret_cast<const short8*>(ap + (size_t)((st < 15) ? st + 1 : st) * 1024);
#pragma unroll
    for (int v = 0; v < 4; ++v) {
      floatx4 z = {0.f, 0.f, 0.f, 0.f};
      z = __builtin_amdgcn_mfma_f32_16x16x32_bf16(ac, bv[v], z, 0, 0, 0);
      ls[v] += (__builtin_amdgcn_exp2f(z[0]) + __builtin_amdgcn_exp2f(z[1]))
             + (__builtin_amdgcn_exp2f(z[2]) + __builtin_amdgcn_exp2f(z[3]));
    }
    ac = an;
  }
#pragma unroll
  for (int v = 0; v < 4; ++v) {
    ls[v] += __shfl_xor(ls[v], 16);
    ls[v] += __shfl_xor(ls[v], 32);
  }
  if (quad == 0) {
#pragma unroll
    for (int v = 0; v < 4; ++v)
      lpart[((size_t)iz * B_ + b) * N_ + jw + v * 16 + n15] = ls[v];
  }
}

// ---------------- pass B: pv, LDS-staged, inline linv (no scale_g kernel) ------------
// 1D grid 1024, XCD swizzle: blocks sharing (b,jq) keep bid%8 fixed -> same XCD L2.
// s_linv[j] = bf16(1/l_j) computed in prologue; exp outputs scaled before pack.
#define PHI_PITCH 40   // 32 elem + 8 pad
#define G_PITCH   136  // 128 elem + 8 pad
__global__ void __launch_bounds__(256, 4) attn_pv_k(
    const unsigned short* __restrict__ thph, const unsigned short* __restrict__ g16,
    const float* __restrict__ lpart, unsigned short* __restrict__ y2p)
{
  const int bid = blockIdx.x;
  const int b  = bid & 3;
  const int jq = (bid >> 2) & 3;
  const int itile = bid >> 4;
  const int t = threadIdx.x, wave = t >> 6, lane = t & 63;
  const int n15 = lane & 15, quad = lane >> 4;
  const int iw = itile * 64 + wave * 16;
  const unsigned short* base = thph + (size_t)b * N_ * 64;
  const unsigned short* gs   = g16  + (size_t)b * 32 * N_;
  __shared__ unsigned short phi_lds[2][128 * PHI_PITCH];
  __shared__ unsigned short g_lds[2][32 * G_PITCH];
  __shared__ unsigned short s_linv[1024];

  const short8 bth = *reinterpret_cast<const short8*>(base + (size_t)(iw + n15) * 64 + quad * 8);
  floatx4 Y0 = {0.f, 0.f, 0.f, 0.f}, Y1 = {0.f, 0.f, 0.f, 0.f};

  const int rphi = wave * 32 + (lane >> 2), cph = lane & 3;
  const int cg   = wave * 8  + (lane >> 4), chg = lane & 15;

  uint4 sp0, sp1, sg0, sg1;
  const int jbase = jq * 1024;
  sp0 = *reinterpret_cast<const uint4*>(base + (size_t)(jbase + rphi) * 64 + 32 + cph * 8);
  sp1 = *reinterpret_cast<const uint4*>(base + (size_t)(jbase + rphi + 16) * 64 + 32 + cph * 8);
  sg0 = *reinterpret_cast<const uint4*>(gs + (size_t)cg * N_ + jbase + chg * 8);
  sg1 = *reinterpret_cast<const uint4*>(gs + (size_t)(cg + 4) * N_ + jbase + chg * 8);
  // inline linv: thread t covers j = jbase + t*4 .. +3
  {
    float4 acc = {0.f, 0.f, 0.f, 0.f};
#pragma unroll
    for (int iz = 0; iz < 16; ++iz) {
      float4 lp = *reinterpret_cast<const float4*>(
          lpart + ((size_t)iz * B_ + b) * N_ + jbase + t * 4);
      acc.x += lp.x; acc.y += lp.y; acc.z += lp.z; acc.w += lp.w;
    }
    unsigned short pk[4];
    pk[0] = f2bf(1.f / acc.x); pk[1] = f2bf(1.f / acc.y);
    pk[2] = f2bf(1.f / acc.z); pk[3] = f2bf(1.f / acc.w);
    *reinterpret_cast<uint2*>(&s_linv[t * 4]) = *reinterpret_cast<uint2*>(pk);
  }
  *reinterpret_cast<uint4*>(&phi_lds[0][rphi * PHI_PITCH + cph * 8]) = sp0;
  *reinterpret_cast<uint4*>(&phi_lds[0][(rphi + 16) * PHI_PITCH + cph * 8]) = sp1;
  *reinterpret_cast<uint4*>(&g_lds[0][cg * G_PITCH + chg * 8]) = sg0;
  *reinterpret_cast<uint4*>(&g_lds[0][(cg + 4) * G_PITCH + chg * 8]) = sg1;
  __syncthreads();

  int j0 = jbase;
  for (int ch = 0; ch < 8; ++ch, j0 += 128) {
    const int cur = ch & 1;
    if (ch < 7) {
      const int jn = j0 + 128;
      sp0 = *reinterpret_cast<const uint4*>(base + (size_t)(jn + rphi) * 64 + 32 + cph * 8);
      sp1 = *reinterpret_cast<const uint4*>(base + (size_t)(jn + rphi + 16) * 64 + 32 + cph * 8);
      sg0 = *reinterpret_cast<const uint4*>(gs + (size_t)cg * N_ + jn + chg * 8);
      sg1 = *reinterpret_cast<const uint4*>(gs + (size_t)(cg + 4) * N_ + jn + chg * 8);
    }
    const unsigned short* phb = &phi_lds[cur][0];
    const unsigned short* glb = &g_lds[cur][0];
    unsigned pk[8][2];
#pragma unroll
    for (int jt = 0; jt < 8; ++jt) {
      short8 aph = *reinterpret_cast<const short8*>(phb + (jt * 16 + n15) * PHI_PITCH + quad * 8);
      floatx4 z = {0.f, 0.f, 0.f, 0.f};
      z = __builtin_amdgcn_mfma_f32_16x16x32_bf16(aph, bth, z, 0, 0, 0);
      // linv broadcast: j_rel = ch*128 + jt*16 + quad*4
      uint2 lv = *reinterpret_cast<const uint2*>(&s_linv[ch * 128 + jt * 16 + quad * 4]);
      float l0 = bf2f((unsigned short)(lv.x & 0xffffu)), l1 = bf2f((unsigned short)(lv.x >> 16));
      float l2 = bf2f((unsigned short)(lv.y & 0xffffu)), l3 = bf2f((unsigned short)(lv.y >> 16));
      float e0 = __builtin_amdgcn_exp2f(z[0]) * l0, e1 = __builtin_amdgcn_exp2f(z[1]) * l1;
      float e2 = __builtin_amdgcn_exp2f(z[2]) * l2, e3 = __builtin_amdgcn_exp2f(z[3]) * l3;
      pk[jt][0] = __builtin_amdgcn_perm(__float_as_uint(e1), __float_as_uint(e0), 0x07060302);
      pk[jt][1] = __builtin_amdgcn_perm(__float_as_uint(e3), __float_as_uint(e2), 0x07060302);
    }
#pragma unroll
    for (int sg = 0; sg < 4; ++sg) {
      union { unsigned u[4]; short8 v; } pa, gb0, gb1;
      pa.u[0] = pk[2 * sg][0];     pa.u[1] = pk[2 * sg][1];
      pa.u[2] = pk[2 * sg + 1][0]; pa.u[3] = pk[2 * sg + 1][1];
      const unsigned short* gr0 = glb + n15 * G_PITCH + sg * 32 + quad * 4;
      const unsigned short* gr1 = glb + (16 + n15) * G_PITCH + sg * 32 + quad * 4;
      uint2 lo0 = *reinterpret_cast<const uint2*>(gr0);
      uint2 hi0 = *reinterpret_cast<const uint2*>(gr0 + 16);
      uint2 lo1 = *reinterpret_cast<const uint2*>(gr1);
      uint2 hi1 = *reinterpret_cast<const uint2*>(gr1 + 16);
      gb0.u[0] = lo0.x; gb0.u[1] = lo0.y; gb0.u[2] = hi0.x; gb0.u[3] = hi0.y;
      gb1.u[0] = lo1.x; gb1.u[1] = lo1.y; gb1.u[2] = hi1.x; gb1.u[3] = hi1.y;
      Y0 = __builtin_amdgcn_mfma_f32_16x16x32_bf16(pa.v, gb0.v, Y0, 0, 0, 0);
      Y1 = __builtin_amdgcn_mfma_f32_16x16x32_bf16(pa.v, gb1.v, Y1, 0, 0, 0);
    }
    if (ch < 7) {
      const int nb = cur ^ 1;
      *reinterpret_cast<uint4*>(&phi_lds[nb][rphi * PHI_PITCH + cph * 8]) = sp0;
      *reinterpret_cast<uint4*>(&phi_lds[nb][(rphi + 16) * PHI_PITCH + cph * 8]) = sp1;
      *reinterpret_cast<uint4*>(&g_lds[nb][cg * G_PITCH + chg * 8]) = sg0;
      *reinterpret_cast<uint4*>(&g_lds[nb][(cg + 4) * G_PITCH + chg * 8]) = sg1;
    }
    __syncthreads();
  }
  unsigned w0[2], w1[2];
  w0[0] = ((unsigned)f2bf(Y0[1]) << 16) | f2bf(Y0[0]);
  w0[1] = ((unsigned)f2bf(Y0[3]) << 16) | f2bf(Y0[2]);
  w1[0] = ((unsigned)f2bf(Y1[1]) << 16) | f2bf(Y1[0]);
  w1[1] = ((unsigned)f2bf(Y1[3]) << 16) | f2bf(Y1[2]);
  *reinterpret_cast<uint2*>(
      y2p + (((size_t)jq * B_ + b) * 32 + n15) * N_ + iw + quad * 4) =
      *reinterpret_cast<uint2*>(w0);
  *reinterpret_cast<uint2*>(
      y2p + (((size_t)jq * B_ + b) * 32 + 16 + n15) * N_ + iw + quad * 4) =
      *reinterpret_cast<uint2*>(w1);
}

// ---------------- final: out = (W_y(y2) + am) * x ----------------
__global__ void __launch_bounds__(256) final_k(
    const unsigned short* __restrict__ y2p, const float* __restrict__ w_w,
    const float* __restrict__ w_b, const unsigned short* __restrict__ am_cl,
    const float* __restrict__ x, float* __restrict__ out)
{
  const int n0 = (blockIdx.x * 256 + threadIdx.x) * 2;
  const int o0 = blockIdx.y * 8;
  const int b  = blockIdx.z;
  float a0[8], a1[8];
#pragma unroll
  for (int u = 0; u < 8; ++u) { a0[u] = w_b[o0 + u]; a1[u] = a0[u]; }
  for (int c = 0; c < 32; ++c) {
    float s0 = 0.f, s1 = 0.f;
#pragma unroll
    for (int ph = 0; ph < 4; ++ph) {
      unsigned v = *reinterpret_cast<const unsigned*>(
          y2p + (((size_t)ph * B_ + b) * 32 + c) * N_ + n0);
      s0 += bf2f((unsigned short)(v & 0xffffu));
      s1 += bf2f((unsigned short)(v >> 16));
    }
#pragma unroll
    for (int u = 0; u < 8; ++u) {
      float wv = w_w[(o0 + u) * 32 + c];
      a0[u] += wv * s0; a1[u] += wv * s1;
    }
  }
  const short8 am0 = *reinterpret_cast<const short8*>(am_cl + ((size_t)b * N_ + n0) * 64 + o0);
  const short8 am1 = *reinterpret_cast<const short8*>(am_cl + ((size_t)b * N_ + n0 + 1) * 64 + o0);
#pragma unroll
  for (int u = 0; u < 8; ++u) {
    size_t off = ((size_t)b * 64 + o0 + u) * N_ + n0;
    float2 xv = *reinterpret_cast<const float2*>(x + off);
    float2 ov;
    ov.x = (a0[u] + bf2f((unsigned short)am0[u])) * xv.x;
    ov.y = (a1[u] + bf2f((unsigned short)am1[u])) * xv.y;
    *reinterpret_cast<float2*>(out + off) = ov;
  }
}

extern "C" void kernel_launch(void* const* d_in, const int* in_sizes, int n_in,
                              void* d_out, int out_size, void* d_ws, size_t ws_size,
                              hipStream_t stream) {
  const float* x    = (const float*)d_in[0];
  const float* d1_w = (const float*)d_in[1];
  const float* d1_b = (const float*)d_in[2];
  const float* d2_w = (const float*)d_in[3];
  const float* d2_b = (const float*)d_in[4];
  const float* d3_w = (const float*)d_in[5];
  const float* d3_b = (const float*)d_in[6];
  const float* g_w  = (const float*)d_in[7];
  const float* g_b  = (const float*)d_in[8];
  const float* th_w = (const float*)d_in[9];
  const float* th_b = (const float*)d_in[10];
  const float* ph_w = (const float*)d_in[11];
  const float* ph_b = (const float*)d_in[12];
  const float* w_w  = (const float*)d_in[13];
  const float* w_b  = (const float*)d_in[14];
  float* out = (float*)d_out;

  char* p = (char*)d_ws;
  unsigned short* am_cl = (unsigned short*)p;  p += (size_t)B_ * N_ * 64 * 2;        // 2 MB
  unsigned short* thph  = (unsigned short*)p;  p += (size_t)B_ * N_ * 64 * 2;        // 2 MB
  unsigned short* g16   = (unsigned short*)p;  p += (size_t)B_ * 32 * N_ * 2;        // 1 MB
  float* lpart          = (float*)p;           p += (size_t)16 * B_ * N_ * 4;        // 1 MB
  unsigned short* y2p   = (unsigned short*)p;  p += (size_t)4 * B_ * 32 * N_ * 2;    // 4 MB
  float* y3cl           = (float*)p;           p += (size_t)B_ * 64 * 64 * 4;        // 64 KB
  unsigned short* wpk   = (unsigned short*)p;  p += (size_t)3 * 36864 * 2;
  unsigned short* wproj = (unsigned short*)p;  p += (size_t)96 * 64 * 2;
  float* bproj          = (float*)p;           p += (size_t)96 * 4;
  unsigned short* xclp  = (unsigned short*)p;  p += (size_t)B_ * 66 * 66 * 64 * 2;
  unsigned short* y1clp = (unsigned short*)p;  p += (size_t)B_ * 34 * 34 * 64 * 2;
  unsigned short* y2clp = (unsigned short*)p;  p += (size_t)B_ * 18 * 18 * 64 * 2;

  pack_xw_k<<<272, 256, 0, stream>>>(x, xclp, y1clp, y2clp,
                                     d1_w, d2_w, d3_w, th_w, ph_w, g_w,
                                     th_b, ph_b, g_b, wpk, wproj, bproj);
  convmf_k<66, 32, true,  true ><<<1024, 64, 0, stream>>>(xclp,  wpk,             d1_b, y1clp, nullptr);
  convmf_k<34, 16, true,  true ><<<256,  64, 0, stream>>>(y1clp, wpk + 36864,     d2_b, y2clp, nullptr);
  convmf_k<18,  8, false, false><<<64,   64, 0, stream>>>(y2clp, wpk + 2 * 36864, d3_b, nullptr, y3cl);
  upsproj_k<<<256, 256, 0, stream>>>(y3cl, x, wproj, bproj, am_cl, thph, g16);
  attn_stats_k<<<1024, 256, 0, stream>>>(thph, lpart);
  attn_pv_k<<<1024, 256, 0, stream>>>(thph, g16, lpart, y2p);
  final_k<<<dim3(8, 8, 4), 256, 0, stream>>>(y2p, w_w, w_b, am_cl, x, out);
}

// Round 11
// 159.868 us; speedup vs baseline: 1.1183x; 1.0015x over previous
//
#include <hip/hip_runtime.h>

#define B_ 4
#define C_ 64
#define IC_ 32
#define N_ 4096
#define LOG2E 1.44269504088896341f

typedef __attribute__((ext_vector_type(8))) short short8;
typedef __attribute__((ext_vector_type(4))) float floatx4;

__device__ __forceinline__ unsigned short f2bf(float f) {
  unsigned u = __float_as_uint(f);
  u += 0x7FFFu + ((u >> 16) & 1u);   // round-to-nearest-even
  return (unsigned short)(u >> 16);
}
__device__ __forceinline__ float bf2f(unsigned short h) {
  return __uint_as_float(((unsigned)h) << 16);
}

// ---------------- pack: x -> padded cl bf16; weights; conv pad rings ----------------
__global__ void __launch_bounds__(256) pack_xw_k(
    const float* __restrict__ x, unsigned short* __restrict__ xclp,
    unsigned short* __restrict__ y1clp, unsigned short* __restrict__ y2clp,
    const float* __restrict__ d1_w, const float* __restrict__ d2_w, const float* __restrict__ d3_w,
    const float* __restrict__ th_w, const float* __restrict__ ph_w, const float* __restrict__ g_w,
    const float* __restrict__ th_b, const float* __restrict__ ph_b, const float* __restrict__ g_b,
    unsigned short* __restrict__ wpk, unsigned short* __restrict__ wproj, float* __restrict__ bproj)
{
  __shared__ float s[64][65];
  const int t = threadIdx.x;
  if (blockIdx.x < 256) {
    const int b = blockIdx.x >> 6, h = blockIdx.x & 63;
    for (int idx = t; idx < 4096; idx += 256) {
      int c = idx >> 6, w = idx & 63;
      s[c][w] = x[((size_t)(b * 64 + c)) * 4096 + h * 64 + w];
    }
    __syncthreads();
    for (int idx = t; idx < 4096; idx += 256) {
      int w = idx >> 6, c = idx & 63;
      xclp[(((size_t)b * 66 + h + 1) * 66 + (w + 1)) * 64 + c] = f2bf(s[c][w]);
    }
  } else {
    const int tid = (blockIdx.x - 256) * 256 + t;
    for (int idx = tid; idx < 3 * 36864; idx += 16 * 256) {
      int cv = idx / 36864, r = idx % 36864;
      int tap = r / 4096, r2 = r % 4096;
      int oc = r2 >> 6, ic = r2 & 63;
      const float* src = (cv == 0) ? d1_w : (cv == 1) ? d2_w : d3_w;
      wpk[(size_t)cv * 36864 + tap * 4096 + oc * 64 + ic] = f2bf(src[oc * 576 + ic * 9 + tap]);
    }
    for (int idx = tid; idx < 6144; idx += 16 * 256) {
      int m = idx >> 6, ic = idx & 63;
      float v = (m < 32) ? LOG2E * th_w[m * 64 + ic]
              : (m < 64) ? ph_w[(m - 32) * 64 + ic]
                         : g_w[(m - 64) * 64 + ic];
      wproj[m * 64 + ic] = f2bf(v);
    }
    for (int m = tid; m < 96; m += 16 * 256) {
      bproj[m] = (m < 32) ? LOG2E * th_b[m] : (m < 64) ? ph_b[m - 32] : g_b[m - 64];
    }
    // zero pad rings of the three padded conv buffers (replaces memset node)
#pragma unroll
    for (int img = 0; img < 3; ++img) {
      const int P = (img == 0) ? 66 : (img == 1) ? 34 : 18;
      unsigned short* dst = (img == 0) ? xclp : (img == 1) ? y1clp : y2clp;
      const int ring = 2 * P + 2 * (P - 2);
      const int tot = B_ * ring * 64;
      for (int idx = tid; idx < tot; idx += 16 * 256) {
        int c = idx & 63, r = idx >> 6;
        int k = r % ring, b = r / ring;
        int h, w;
        if (k < P)          { h = 0;     w = k; }
        else if (k < 2 * P) { h = P - 1; w = k - P; }
        else { int q = k - 2 * P; h = 1 + (q >> 1); w = (q & 1) ? (P - 1) : 0; }
        dst[(((size_t)b * P + h) * P + w) * 64 + c] = 0;
      }
    }
  }
}

// ---------------- implicit-GEMM conv 3x3 s2, MFMA bf16, 256 thr (r3 form) -----------
// Block = 4 waves = 4 oc-tiles, one 16-output tile: the 4 waves issue identical
// xpix addresses -> L1 broadcast, 4x fewer L2 requests than 1-wave blocks.
template<int IN_PW, int OUT_H, bool LRELU, bool OUT_BF16>
__global__ void __launch_bounds__(256) convmf_k(
    const unsigned short* __restrict__ xin, const unsigned short* __restrict__ wp,
    const float* __restrict__ bias, unsigned short* __restrict__ obf,
    float* __restrict__ of32)
{
  constexpr int NTILES = OUT_H * OUT_H / 16;
  const int t = threadIdx.x, wave = t >> 6, lane = t & 63;
  const int n15 = lane & 15, quad = lane >> 4;
  const int otile = blockIdx.x % NTILES;
  const int b = blockIdx.x / NTILES;
  const int o = otile * 16 + n15;
  const int oh = o / OUT_H, ow = o % OUT_H;
  const unsigned short* xb = xin + (size_t)b * IN_PW * IN_PW * 64;
  floatx4 acc = {0.f, 0.f, 0.f, 0.f};
#pragma unroll
  for (int tap = 0; tap < 9; ++tap) {
    const int kh = tap / 3, kw = tap % 3;
    const unsigned short* xpix = xb + ((size_t)(oh * 2 + kh) * IN_PW + (ow * 2 + kw)) * 64;
#pragma unroll
    for (int ks = 0; ks < 2; ++ks) {
      short8 af = *reinterpret_cast<const short8*>(
          wp + ((size_t)tap * 64 + wave * 16 + n15) * 64 + ks * 32 + quad * 8);
      short8 bf = *reinterpret_cast<const short8*>(xpix + ks * 32 + quad * 8);
      acc = __builtin_amdgcn_mfma_f32_16x16x32_bf16(af, bf, acc, 0, 0, 0);
    }
  }
  const float4 bv = *reinterpret_cast<const float4*>(bias + wave * 16 + quad * 4);
  float v[4] = {acc[0] + bv.x, acc[1] + bv.y, acc[2] + bv.z, acc[3] + bv.w};
  if (LRELU) {
#pragma unroll
    for (int r = 0; r < 4; ++r) v[r] = (v[r] >= 0.f) ? v[r] : 0.2f * v[r];
  }
  if (OUT_BF16) {
    constexpr int OPW = OUT_H + 2;
    unsigned short pk[4];
#pragma unroll
    for (int r = 0; r < 4; ++r) pk[r] = f2bf(v[r]);
    *reinterpret_cast<uint2*>(
        obf + (((size_t)b * OPW + oh + 1) * OPW + (ow + 1)) * 64 + wave * 16 + quad * 4) =
        *reinterpret_cast<uint2*>(pk);
  } else {
    *reinterpret_cast<float4*>(
        of32 + ((size_t)b * OUT_H * OUT_H + o) * 64 + wave * 16 + quad * 4) =
        *reinterpret_cast<float4*>(v);
  }
}

// ---------------- fused: bilinear upsample + sigmoid gate + 1x1 proj MFMA ------------
__global__ void __launch_bounds__(256) upsproj_k(
    const float* __restrict__ y3cl, const float* __restrict__ x,
    const unsigned short* __restrict__ wproj, const float* __restrict__ bproj,
    unsigned short* __restrict__ am_cl, unsigned short* __restrict__ thph,
    unsigned short* __restrict__ g16)
{
  const int b = blockIdx.x >> 6, oh = blockIdx.x & 63;
  const int t = threadIdx.x;
  __shared__ float s0[512], s1[512];
  __shared__ unsigned short s_am[64][72];
  float sh = (oh + 0.5f) * 0.125f - 0.5f;
  float fh = floorf(sh); float ah = sh - fh; int h0 = (int)fh;
  int h0c = min(7, max(0, h0)), h1c = min(7, max(0, h0 + 1));
  const float* yb = y3cl + (size_t)b * 4096;
  for (int i = t; i < 512; i += 256) { s0[i] = yb[h0c * 512 + i]; s1[i] = yb[h1c * 512 + i]; }
  __syncthreads();
  {
    const int ow = t >> 2, cq = t & 3;
    float sw = (ow + 0.5f) * 0.125f - 0.5f;
    float fw = floorf(sw); float aw = sw - fw; int w0 = (int)fw;
    int w0c = min(7, max(0, w0)), w1c = min(7, max(0, w0 + 1));
    const int n = oh * 64 + ow;
    const float* xb = x + (size_t)b * 64 * 4096 + n;
    unsigned short* ap = am_cl + ((size_t)b * N_ + n) * 64 + cq * 16;
#pragma unroll
    for (int u = 0; u < 4; ++u) {
      int c0 = cq * 16 + u * 4;
      float4 a00 = *reinterpret_cast<const float4*>(&s0[w0c * 64 + c0]);
      float4 a01 = *reinterpret_cast<const float4*>(&s0[w1c * 64 + c0]);
      float4 a10 = *reinterpret_cast<const float4*>(&s1[w0c * 64 + c0]);
      float4 a11 = *reinterpret_cast<const float4*>(&s1[w1c * 64 + c0]);
      float i0[4] = {a00.x * (1.f - aw) + a01.x * aw, a00.y * (1.f - aw) + a01.y * aw,
                     a00.z * (1.f - aw) + a01.z * aw, a00.w * (1.f - aw) + a01.w * aw};
      float i1[4] = {a10.x * (1.f - aw) + a11.x * aw, a10.y * (1.f - aw) + a11.y * aw,
                     a10.z * (1.f - aw) + a11.z * aw, a10.w * (1.f - aw) + a11.w * aw};
      unsigned short pk[4];
#pragma unroll
      for (int vi = 0; vi < 4; ++vi) {
        float vv = i0[vi] * (1.f - ah) + i1[vi] * ah;
        float xv = xb[(size_t)(c0 + vi) * 4096];
        float sig = 1.f / (1.f + __expf(-vv));
        pk[vi] = f2bf(sig * xv);
      }
      uint2 pkt = *reinterpret_cast<uint2*>(pk);
      *reinterpret_cast<uint2*>(ap + u * 4) = pkt;
      *reinterpret_cast<uint2*>(&s_am[ow][c0]) = pkt;
    }
  }
  __syncthreads();
  const int wave = t >> 6, lane = t & 63;
  const int n15 = lane & 15, quad = lane >> 4;
  const int n = oh * 64 + wave * 16 + n15;
  const unsigned short* srow = &s_am[wave * 16 + n15][0];
  const short8 bf0 = *reinterpret_cast<const short8*>(srow + quad * 8);
  const short8 bf1 = *reinterpret_cast<const short8*>(srow + 32 + quad * 8);
#pragma unroll
  for (int mt = 0; mt < 6; ++mt) {
    short8 a0 = *reinterpret_cast<const short8*>(wproj + ((size_t)mt * 16 + n15) * 64 + quad * 8);
    short8 a1 = *reinterpret_cast<const short8*>(wproj + ((size_t)mt * 16 + n15) * 64 + 32 + quad * 8);
    floatx4 acc = {0.f, 0.f, 0.f, 0.f};
    acc = __builtin_amdgcn_mfma_f32_16x16x32_bf16(a0, bf0, acc, 0, 0, 0);
    acc = __builtin_amdgcn_mfma_f32_16x16x32_bf16(a1, bf1, acc, 0, 0, 0);
    const float4 bv = *reinterpret_cast<const float4*>(bproj + mt * 16 + quad * 4);
    float v[4] = {acc[0] + bv.x, acc[1] + bv.y, acc[2] + bv.z, acc[3] + bv.w};
    if (mt < 4) {
      unsigned short pk[4];
#pragma unroll
      for (int r = 0; r < 4; ++r) pk[r] = f2bf(v[r]);
      *reinterpret_cast<uint2*>(thph + ((size_t)b * N_ + n) * 64 + mt * 16 + quad * 4) =
          *reinterpret_cast<uint2*>(pk);
    } else {
#pragma unroll
      for (int r = 0; r < 4; ++r)
        g16[((size_t)b * 32 + (mt - 4) * 16 + quad * 4 + r) * N_ + n] = f2bf(v[r]);
    }
  }
}

// ---------------- pass A: l_j = sum_i exp2(S'_ij), partials over 16 i-slices ---------
__global__ void __launch_bounds__(256) attn_stats_k(
    const unsigned short* __restrict__ thph, float* __restrict__ lpart)
{
  const int b  = blockIdx.y;
  const int iz = blockIdx.z;
  const int t = threadIdx.x, wave = t >> 6, lane = t & 63;
  const int n15 = lane & 15, quad = lane >> 4;
  const int jw = blockIdx.x * 256 + wave * 64;
  const unsigned short* base = thph + (size_t)b * N_ * 64;
  short8 bv[4];
#pragma unroll
  for (int v = 0; v < 4; ++v)
    bv[v] = *reinterpret_cast<const short8*>(base + (size_t)(jw + v * 16 + n15) * 64 + 32 + quad * 8);
  float ls[4] = {0.f, 0.f, 0.f, 0.f};
  const unsigned short* ap = base + (size_t)(iz * 256 + n15) * 64 + quad * 8;
  short8 ac = *reinterpret_cast<const short8*>(ap);
  for (int st = 0; st < 16; ++st) {
    short8 an = *reinterpret_cast<const short8*>(ap + (size_t)((st < 15) ? st + 1 : st) * 1024);
#pragma unroll
    for (int v = 0; v < 4; ++v) {
      floatx4 z = {0.f, 0.f, 0.f, 0.f};
      z = __builtin_amdgcn_mfma_f32_16x16x32_bf16(ac, bv[v], z, 0, 0, 0);
      ls[v] += (__builtin_amdgcn_exp2f(z[0]) + __builtin_amdgcn_exp2f(z[1]))
             + (__builtin_amdgcn_exp2f(z[2]) + __builtin_amdgcn_exp2f(z[3]));
    }
    ac = an;
  }
#pragma unroll
  for (int v = 0; v < 4; ++v) {
    ls[v] += __shfl_xor(ls[v], 16);
    ls[v] += __shfl_xor(ls[v], 32);
  }
  if (quad == 0) {
#pragma unroll
    for (int v = 0; v < 4; ++v)
      lpart[((size_t)iz * B_ + b) * N_ + jw + v * 16 + n15] = ls[v];
  }
}

// ---------------- fold softmax denom into g: g[c][j] *= 1/l_j (in place) ----------------
__global__ void __launch_bounds__(256) scale_g_k(
    const float* __restrict__ lpart, unsigned short* __restrict__ g16)
{
  const int b = blockIdx.y;
  const int c0 = blockIdx.z * 8;
  const int j = blockIdx.x * 256 + threadIdx.x;
  float l = 0.f;
#pragma unroll
  for (int iz = 0; iz < 16; ++iz) l += lpart[((size_t)iz * B_ + b) * N_ + j];
  const float rl = 1.f / l;
  unsigned short* gp = g16 + ((size_t)b * 32 + c0) * N_ + j;
#pragma unroll
  for (int c = 0; c < 8; ++c) {
    gp[(size_t)c * N_] = f2bf(bf2f(gp[(size_t)c * N_]) * rl);
  }
}

// ---------------- pass B: GEMM-style with block LDS staging (r7-verified) ------------
#define PHI_PITCH 40   // 32 elem + 8 pad
#define G_PITCH   136  // 128 elem + 8 pad
__global__ void __launch_bounds__(256, 4) attn_pv_k(
    const unsigned short* __restrict__ thph, const unsigned short* __restrict__ g16,
    unsigned short* __restrict__ y2p)
{
  const int b  = blockIdx.y;
  const int jq = blockIdx.z;
  const int t = threadIdx.x, wave = t >> 6, lane = t & 63;
  const int n15 = lane & 15, quad = lane >> 4;
  const int iw = blockIdx.x * 64 + wave * 16;
  const unsigned short* base = thph + (size_t)b * N_ * 64;
  const unsigned short* gs   = g16  + (size_t)b * 32 * N_;
  __shared__ unsigned short phi_lds[2][128 * PHI_PITCH];
  __shared__ unsigned short g_lds[2][32 * G_PITCH];

  const short8 bth = *reinterpret_cast<const short8*>(base + (size_t)(iw + n15) * 64 + quad * 8);
  floatx4 Y0 = {0.f, 0.f, 0.f, 0.f}, Y1 = {0.f, 0.f, 0.f, 0.f};

  const int rphi = wave * 32 + (lane >> 2), cph = lane & 3;
  const int cg   = wave * 8  + (lane >> 4), chg = lane & 15;

  uint4 sp0, sp1, sg0, sg1;
  const int jbase = jq * 1024;
  sp0 = *reinterpret_cast<const uint4*>(base + (size_t)(jbase + rphi) * 64 + 32 + cph * 8);
  sp1 = *reinterpret_cast<const uint4*>(base + (size_t)(jbase + rphi + 16) * 64 + 32 + cph * 8);
  sg0 = *reinterpret_cast<const uint4*>(gs + (size_t)cg * N_ + jbase + chg * 8);
  sg1 = *reinterpret_cast<const uint4*>(gs + (size_t)(cg + 4) * N_ + jbase + chg * 8);
  *reinterpret_cast<uint4*>(&phi_lds[0][rphi * PHI_PITCH + cph * 8]) = sp0;
  *reinterpret_cast<uint4*>(&phi_lds[0][(rphi + 16) * PHI_PITCH + cph * 8]) = sp1;
  *reinterpret_cast<uint4*>(&g_lds[0][cg * G_PITCH + chg * 8]) = sg0;
  *reinterpret_cast<uint4*>(&g_lds[0][(cg + 4) * G_PITCH + chg * 8]) = sg1;
  __syncthreads();

  int j0 = jbase;
  for (int ch = 0; ch < 8; ++ch, j0 += 128) {
    const int cur = ch & 1;
    if (ch < 7) {
      const int jn = j0 + 128;
      sp0 = *reinterpret_cast<const uint4*>(base + (size_t)(jn + rphi) * 64 + 32 + cph * 8);
      sp1 = *reinterpret_cast<const uint4*>(base + (size_t)(jn + rphi + 16) * 64 + 32 + cph * 8);
      sg0 = *reinterpret_cast<const uint4*>(gs + (size_t)cg * N_ + jn + chg * 8);
      sg1 = *reinterpret_cast<const uint4*>(gs + (size_t)(cg + 4) * N_ + jn + chg * 8);
    }
    const unsigned short* phb = &phi_lds[cur][0];
    const unsigned short* glb = &g_lds[cur][0];
    unsigned pk[8][2];
#pragma unroll
    for (int jt = 0; jt < 8; ++jt) {
      short8 aph = *reinterpret_cast<const short8*>(phb + (jt * 16 + n15) * PHI_PITCH + quad * 8);
      floatx4 z = {0.f, 0.f, 0.f, 0.f};
      z = __builtin_amdgcn_mfma_f32_16x16x32_bf16(aph, bth, z, 0, 0, 0);
      float e0 = __builtin_amdgcn_exp2f(z[0]), e1 = __builtin_amdgcn_exp2f(z[1]);
      float e2 = __builtin_amdgcn_exp2f(z[2]), e3 = __builtin_amdgcn_exp2f(z[3]);
      pk[jt][0] = __builtin_amdgcn_perm(__float_as_uint(e1), __float_as_uint(e0), 0x07060302);
      pk[jt][1] = __builtin_amdgcn_perm(__float_as_uint(e3), __float_as_uint(e2), 0x07060302);
    }
#pragma unroll
    for (int sg = 0; sg < 4; ++sg) {
      union { unsigned u[4]; short8 v; } pa, gb0, gb1;
      pa.u[0] = pk[2 * sg][0];     pa.u[1] = pk[2 * sg][1];
      pa.u[2] = pk[2 * sg + 1][0]; pa.u[3] = pk[2 * sg + 1][1];
      const unsigned short* gr0 = glb + n15 * G_PITCH + sg * 32 + quad * 4;
      const unsigned short* gr1 = glb + (16 + n15) * G_PITCH + sg * 32 + quad * 4;
      uint2 lo0 = *reinterpret_cast<const uint2*>(gr0);
      uint2 hi0 = *reinterpret_cast<const uint2*>(gr0 + 16);
      uint2 lo1 = *reinterpret_cast<const uint2*>(gr1);
      uint2 hi1 = *reinterpret_cast<const uint2*>(gr1 + 16);
      gb0.u[0] = lo0.x; gb0.u[1] = lo0.y; gb0.u[2] = hi0.x; gb0.u[3] = hi0.y;
      gb1.u[0] = lo1.x; gb1.u[1] = lo1.y; gb1.u[2] = hi1.x; gb1.u[3] = hi1.y;
      Y0 = __builtin_amdgcn_mfma_f32_16x16x32_bf16(pa.v, gb0.v, Y0, 0, 0, 0);
      Y1 = __builtin_amdgcn_mfma_f32_16x16x32_bf16(pa.v, gb1.v, Y1, 0, 0, 0);
    }
    if (ch < 7) {
      const int nb = cur ^ 1;
      *reinterpret_cast<uint4*>(&phi_lds[nb][rphi * PHI_PITCH + cph * 8]) = sp0;
      *reinterpret_cast<uint4*>(&phi_lds[nb][(rphi + 16) * PHI_PITCH + cph * 8]) = sp1;
      *reinterpret_cast<uint4*>(&g_lds[nb][cg * G_PITCH + chg * 8]) = sg0;
      *reinterpret_cast<uint4*>(&g_lds[nb][(cg + 4) * G_PITCH + chg * 8]) = sg1;
    }
    __syncthreads();
  }
  unsigned w0[2], w1[2];
  w0[0] = ((unsigned)f2bf(Y0[1]) << 16) | f2bf(Y0[0]);
  w0[1] = ((unsigned)f2bf(Y0[3]) << 16) | f2bf(Y0[2]);
  w1[0] = ((unsigned)f2bf(Y1[1]) << 16) | f2bf(Y1[0]);
  w1[1] = ((unsigned)f2bf(Y1[3]) << 16) | f2bf(Y1[2]);
  *reinterpret_cast<uint2*>(
      y2p + (((size_t)jq * B_ + b) * 32 + n15) * N_ + iw + quad * 4) =
      *reinterpret_cast<uint2*>(w0);
  *reinterpret_cast<uint2*>(
      y2p + (((size_t)jq * B_ + b) * 32 + 16 + n15) * N_ + iw + quad * 4) =
      *reinterpret_cast<uint2*>(w1);
}

// ---------------- final: out = (W_y(y2) + am) * x ----------------
__global__ void __launch_bounds__(256) final_k(
    const unsigned short* __restrict__ y2p, const float* __restrict__ w_w,
    const float* __restrict__ w_b, const unsigned short* __restrict__ am_cl,
    const float* __restrict__ x, float* __restrict__ out)
{
  const int n0 = (blockIdx.x * 256 + threadIdx.x) * 2;
  const int o0 = blockIdx.y * 8;
  const int b  = blockIdx.z;
  float a0[8], a1[8];
#pragma unroll
  for (int u = 0; u < 8; ++u) { a0[u] = w_b[o0 + u]; a1[u] = a0[u]; }
  for (int c = 0; c < 32; ++c) {
    float s0 = 0.f, s1 = 0.f;
#pragma unroll
    for (int ph = 0; ph < 4; ++ph) {
      unsigned v = *reinterpret_cast<const unsigned*>(
          y2p + (((size_t)ph * B_ + b) * 32 + c) * N_ + n0);
      s0 += bf2f((unsigned short)(v & 0xffffu));
      s1 += bf2f((unsigned short)(v >> 16));
    }
#pragma unroll
    for (int u = 0; u < 8; ++u) {
      float wv = w_w[(o0 + u) * 32 + c];
      a0[u] += wv * s0; a1[u] += wv * s1;
    }
  }
  const short8 am0 = *reinterpret_cast<const short8*>(am_cl + ((size_t)b * N_ + n0) * 64 + o0);
  const short8 am1 = *reinterpret_cast<const short8*>(am_cl + ((size_t)b * N_ + n0 + 1) * 64 + o0);
#pragma unroll
  for (int u = 0; u < 8; ++u) {
    size_t off = ((size_t)b * 64 + o0 + u) * N_ + n0;
    float2 xv = *reinterpret_cast<const float2*>(x + off);
    float2 ov;
    ov.x = (a0[u] + bf2f((unsigned short)am0[u])) * xv.x;
    ov.y = (a1[u] + bf2f((unsigned short)am1[u])) * xv.y;
    *reinterpret_cast<float2*>(out + off) = ov;
  }
}

extern "C" void kernel_launch(void* const* d_in, const int* in_sizes, int n_in,
                              void* d_out, int out_size, void* d_ws, size_t ws_size,
                              hipStream_t stream) {
  const float* x    = (const float*)d_in[0];
  const float* d1_w = (const float*)d_in[1];
  const float* d1_b = (const float*)d_in[2];
  const float* d2_w = (const float*)d_in[3];
  const float* d2_b = (const float*)d_in[4];
  const float* d3_w = (const float*)d_in[5];
  const float* d3_b = (const float*)d_in[6];
  const float* g_w  = (const float*)d_in[7];
  const float* g_b  = (const float*)d_in[8];
  const float* th_w = (const float*)d_in[9];
  const float* th_b = (const float*)d_in[10];
  const float* ph_w = (const float*)d_in[11];
  const float* ph_b = (const float*)d_in[12];
  const float* w_w  = (const float*)d_in[13];
  const float* w_b  = (const float*)d_in[14];
  float* out = (float*)d_out;

  char* p = (char*)d_ws;
  unsigned short* am_cl = (unsigned short*)p;  p += (size_t)B_ * N_ * 64 * 2;        // 2 MB
  unsigned short* thph  = (unsigned short*)p;  p += (size_t)B_ * N_ * 64 * 2;        // 2 MB
  unsigned short* g16   = (unsigned short*)p;  p += (size_t)B_ * 32 * N_ * 2;        // 1 MB
  float* lpart          = (float*)p;           p += (size_t)16 * B_ * N_ * 4;        // 1 MB
  unsigned short* y2p   = (unsigned short*)p;  p += (size_t)4 * B_ * 32 * N_ * 2;    // 4 MB
  float* y3cl           = (float*)p;           p += (size_t)B_ * 64 * 64 * 4;        // 64 KB
  unsigned short* wpk   = (unsigned short*)p;  p += (size_t)3 * 36864 * 2;
  unsigned short* wproj = (unsigned short*)p;  p += (size_t)96 * 64 * 2;
  float* bproj          = (float*)p;           p += (size_t)96 * 4;
  unsigned short* xclp  = (unsigned short*)p;  p += (size_t)B_ * 66 * 66 * 64 * 2;
  unsigned short* y1clp = (unsigned short*)p;  p += (size_t)B_ * 34 * 34 * 64 * 2;
  unsigned short* y2clp = (unsigned short*)p;  p += (size_t)B_ * 18 * 18 * 64 * 2;

  pack_xw_k<<<272, 256, 0, stream>>>(x, xclp, y1clp, y2clp,
                                     d1_w, d2_w, d3_w, th_w, ph_w, g_w,
                                     th_b, ph_b, g_b, wpk, wproj, bproj);
  convmf_k<66, 32, true,  true ><<<256, 256, 0, stream>>>(xclp,  wpk,             d1_b, y1clp, nullptr);
  convmf_k<34, 16, true,  true ><<<64,  256, 0, stream>>>(y1clp, wpk + 36864,     d2_b, y2clp, nullptr);
  convmf_k<18,  8, false, false><<<16,  256, 0, stream>>>(y2clp, wpk + 2 * 36864, d3_b, nullptr, y3cl);
  upsproj_k<<<256, 256, 0, stream>>>(y3cl, x, wproj, bproj, am_cl, thph, g16);
  attn_stats_k<<<dim3(16, 4, 16), 256, 0, stream>>>(thph, lpart);
  scale_g_k<<<dim3(16, 4, 4), 256, 0, stream>>>(lpart, g16);
  attn_pv_k<<<dim3(64, 4, 4), 256, 0, stream>>>(thph, g16, y2p);
  final_k<<<dim3(8, 8, 4), 256, 0, stream>>>(y2p, w_w, w_b, am_cl, x, out);
}

// Round 12
// 153.214 us; speedup vs baseline: 1.1669x; 1.0434x over previous
//
#include <hip/hip_runtime.h>

#define B_ 4
#define C_ 64
#define IC_ 32
#define N_ 4096
#define LOG2E 1.44269504088896341f

typedef __attribute__((ext_vector_type(8))) short short8;
typedef __attribute__((ext_vector_type(4))) float floatx4;
typedef unsigned short ushort_t;

__device__ __forceinline__ unsigned short f2bf(float f) {
  unsigned u = __float_as_uint(f);
  u += 0x7FFFu + ((u >> 16) & 1u);   // round-to-nearest-even
  return (unsigned short)(u >> 16);
}
__device__ __forceinline__ float bf2f(unsigned short h) {
  return __uint_as_float(((unsigned)h) << 16);
}

// ---------------- fused pack: x -> padded cl bf16; weights -> packed bf16 ----------------
__global__ void __launch_bounds__(256) pack_xw_k(
    const float* __restrict__ x, unsigned short* __restrict__ xclp,
    const float* __restrict__ d1_w, const float* __restrict__ d2_w, const float* __restrict__ d3_w,
    const float* __restrict__ th_w, const float* __restrict__ ph_w, const float* __restrict__ g_w,
    const float* __restrict__ th_b, const float* __restrict__ ph_b, const float* __restrict__ g_b,
    unsigned short* __restrict__ wpk, unsigned short* __restrict__ wproj, float* __restrict__ bproj)
{
  __shared__ float s[64][65];
  const int t = threadIdx.x;
  if (blockIdx.x < 256) {
    const int b = blockIdx.x >> 6, h = blockIdx.x & 63;
    for (int idx = t; idx < 4096; idx += 256) {
      int c = idx >> 6, w = idx & 63;
      s[c][w] = x[((size_t)(b * 64 + c)) * 4096 + h * 64 + w];
    }
    __syncthreads();
    for (int idx = t; idx < 4096; idx += 256) {
      int w = idx >> 6, c = idx & 63;
      xclp[(((size_t)b * 66 + h + 1) * 66 + (w + 1)) * 64 + c] = f2bf(s[c][w]);
    }
  } else {
    const int tid = (blockIdx.x - 256) * 256 + t;
    for (int idx = tid; idx < 3 * 36864; idx += 16 * 256) {
      int cv = idx / 36864, r = idx % 36864;
      int tap = r / 4096, r2 = r % 4096;
      int oc = r2 >> 6, ic = r2 & 63;
      const float* src = (cv == 0) ? d1_w : (cv == 1) ? d2_w : d3_w;
      wpk[(size_t)cv * 36864 + tap * 4096 + oc * 64 + ic] = f2bf(src[oc * 576 + ic * 9 + tap]);
    }
    for (int idx = tid; idx < 6144; idx += 16 * 256) {
      int m = idx >> 6, ic = idx & 63;
      float v = (m < 32) ? LOG2E * th_w[m * 64 + ic]
              : (m < 64) ? ph_w[(m - 32) * 64 + ic]
                         : g_w[(m - 64) * 64 + ic];
      wproj[m * 64 + ic] = f2bf(v);
    }
    for (int m = tid; m < 96; m += 16 * 256) {
      bproj[m] = (m < 32) ? LOG2E * th_b[m] : (m < 64) ? ph_b[m - 32] : g_b[m - 64];
    }
  }
}

// ---------------- implicit-GEMM conv 3x3 s2, 64->64 ch, MFMA bf16, 1 wave/block ------
template<int IN_PW, int OUT_H, bool LRELU, bool OUT_BF16>
__global__ void __launch_bounds__(64) convmf_k(
    const unsigned short* __restrict__ xin, const unsigned short* __restrict__ wp,
    const float* __restrict__ bias, unsigned short* __restrict__ obf,
    float* __restrict__ of32)
{
  constexpr int NTILES = OUT_H * OUT_H / 16;
  const int lane = threadIdx.x;
  const int n15 = lane & 15, quad = lane >> 4;
  int bx = blockIdx.x;
  const int octile = bx & 3; bx >>= 2;
  const int otile = bx % NTILES;
  const int b = bx / NTILES;
  const int o = otile * 16 + n15;
  const int oh = o / OUT_H, ow = o % OUT_H;
  const unsigned short* xb = xin + (size_t)b * IN_PW * IN_PW * 64;
  floatx4 acc = {0.f, 0.f, 0.f, 0.f};
#pragma unroll
  for (int tap = 0; tap < 9; ++tap) {
    const int kh = tap / 3, kw = tap % 3;
    const unsigned short* xpix = xb + ((size_t)(oh * 2 + kh) * IN_PW + (ow * 2 + kw)) * 64;
#pragma unroll
    for (int ks = 0; ks < 2; ++ks) {
      short8 af = *reinterpret_cast<const short8*>(
          wp + ((size_t)tap * 64 + octile * 16 + n15) * 64 + ks * 32 + quad * 8);
      short8 bf = *reinterpret_cast<const short8*>(xpix + ks * 32 + quad * 8);
      acc = __builtin_amdgcn_mfma_f32_16x16x32_bf16(af, bf, acc, 0, 0, 0);
    }
  }
  const float4 bv = *reinterpret_cast<const float4*>(bias + octile * 16 + quad * 4);
  float v[4] = {acc[0] + bv.x, acc[1] + bv.y, acc[2] + bv.z, acc[3] + bv.w};
  if (LRELU) {
#pragma unroll
    for (int r = 0; r < 4; ++r) v[r] = (v[r] >= 0.f) ? v[r] : 0.2f * v[r];
  }
  if (OUT_BF16) {
    constexpr int OPW = OUT_H + 2;
    unsigned short pk[4];
#pragma unroll
    for (int r = 0; r < 4; ++r) pk[r] = f2bf(v[r]);
    *reinterpret_cast<uint2*>(
        obf + (((size_t)b * OPW + oh + 1) * OPW + (ow + 1)) * 64 + octile * 16 + quad * 4) =
        *reinterpret_cast<uint2*>(pk);
  } else {
    *reinterpret_cast<float4*>(
        of32 + ((size_t)b * OUT_H * OUT_H + o) * 64 + octile * 16 + quad * 4) =
        *reinterpret_cast<float4*>(v);
  }
}

// ---------------- fused: bilinear upsample + sigmoid gate + 1x1 proj MFMA ------------
__global__ void __launch_bounds__(256) upsproj_k(
    const float* __restrict__ y3cl, const float* __restrict__ x,
    const unsigned short* __restrict__ wproj, const float* __restrict__ bproj,
    unsigned short* __restrict__ am_cl, unsigned short* __restrict__ thph,
    unsigned short* __restrict__ g16)
{
  const int b = blockIdx.x >> 6, oh = blockIdx.x & 63;
  const int t = threadIdx.x;
  __shared__ float s0[512], s1[512];
  __shared__ unsigned short s_am[64][72];
  float sh = (oh + 0.5f) * 0.125f - 0.5f;
  float fh = floorf(sh); float ah = sh - fh; int h0 = (int)fh;
  int h0c = min(7, max(0, h0)), h1c = min(7, max(0, h0 + 1));
  const float* yb = y3cl + (size_t)b * 4096;
  for (int i = t; i < 512; i += 256) { s0[i] = yb[h0c * 512 + i]; s1[i] = yb[h1c * 512 + i]; }
  __syncthreads();
  {
    const int ow = t >> 2, cq = t & 3;
    float sw = (ow + 0.5f) * 0.125f - 0.5f;
    float fw = floorf(sw); float aw = sw - fw; int w0 = (int)fw;
    int w0c = min(7, max(0, w0)), w1c = min(7, max(0, w0 + 1));
    const int n = oh * 64 + ow;
    const float* xb = x + (size_t)b * 64 * 4096 + n;
    unsigned short* ap = am_cl + ((size_t)b * N_ + n) * 64 + cq * 16;
#pragma unroll
    for (int u = 0; u < 4; ++u) {
      int c0 = cq * 16 + u * 4;
      float4 a00 = *reinterpret_cast<const float4*>(&s0[w0c * 64 + c0]);
      float4 a01 = *reinterpret_cast<const float4*>(&s0[w1c * 64 + c0]);
      float4 a10 = *reinterpret_cast<const float4*>(&s1[w0c * 64 + c0]);
      float4 a11 = *reinterpret_cast<const float4*>(&s1[w1c * 64 + c0]);
      float i0[4] = {a00.x * (1.f - aw) + a01.x * aw, a00.y * (1.f - aw) + a01.y * aw,
                     a00.z * (1.f - aw) + a01.z * aw, a00.w * (1.f - aw) + a01.w * aw};
      float i1[4] = {a10.x * (1.f - aw) + a11.x * aw, a10.y * (1.f - aw) + a11.y * aw,
                     a10.z * (1.f - aw) + a11.z * aw, a10.w * (1.f - aw) + a11.w * aw};
      unsigned short pk[4];
#pragma unroll
      for (int vi = 0; vi < 4; ++vi) {
        float vv = i0[vi] * (1.f - ah) + i1[vi] * ah;
        float xv = xb[(size_t)(c0 + vi) * 4096];
        float sig = 1.f / (1.f + __expf(-vv));
        pk[vi] = f2bf(sig * xv);
      }
      uint2 pkt = *reinterpret_cast<uint2*>(pk);
      *reinterpret_cast<uint2*>(ap + u * 4) = pkt;
      *reinterpret_cast<uint2*>(&s_am[ow][c0]) = pkt;
    }
  }
  __syncthreads();
  const int wave = t >> 6, lane = t & 63;
  const int n15 = lane & 15, quad = lane >> 4;
  const int n = oh * 64 + wave * 16 + n15;
  const unsigned short* srow = &s_am[wave * 16 + n15][0];
  const short8 bf0 = *reinterpret_cast<const short8*>(srow + quad * 8);
  const short8 bf1 = *reinterpret_cast<const short8*>(srow + 32 + quad * 8);
#pragma unroll
  for (int mt = 0; mt < 6; ++mt) {
    short8 a0 = *reinterpret_cast<const short8*>(wproj + ((size_t)mt * 16 + n15) * 64 + quad * 8);
    short8 a1 = *reinterpret_cast<const short8*>(wproj + ((size_t)mt * 16 + n15) * 64 + 32 + quad * 8);
    floatx4 acc = {0.f, 0.f, 0.f, 0.f};
    acc = __builtin_amdgcn_mfma_f32_16x16x32_bf16(a0, bf0, acc, 0, 0, 0);
    acc = __builtin_amdgcn_mfma_f32_16x16x32_bf16(a1, bf1, acc, 0, 0, 0);
    const float4 bv = *reinterpret_cast<const float4*>(bproj + mt * 16 + quad * 4);
    float v[4] = {acc[0] + bv.x, acc[1] + bv.y, acc[2] + bv.z, acc[3] + bv.w};
    if (mt < 4) {
      unsigned short pk[4];
#pragma unroll
      for (int r = 0; r < 4; ++r) pk[r] = f2bf(v[r]);
      *reinterpret_cast<uint2*>(thph + ((size_t)b * N_ + n) * 64 + mt * 16 + quad * 4) =
          *reinterpret_cast<uint2*>(pk);
    } else {
#pragma unroll
      for (int r = 0; r < 4; ++r)
        g16[((size_t)b * 32 + (mt - 4) * 16 + quad * 4 + r) * N_ + n] = f2bf(v[r]);
    }
  }
}

// ---------------- pass A: l_j = sum_i exp2(S'_ij), partials over 16 i-slices ---------
__global__ void __launch_bounds__(256) attn_stats_k(
    const unsigned short* __restrict__ thph, float* __restrict__ lpart)
{
  const int b  = blockIdx.y;
  const int iz = blockIdx.z;
  const int t = threadIdx.x, wave = t >> 6, lane = t & 63;
  const int n15 = lane & 15, quad = lane >> 4;
  const int jw = blockIdx.x * 256 + wave * 64;
  const unsigned short* base = thph + (size_t)b * N_ * 64;
  short8 bv[4];
#pragma unroll
  for (int v = 0; v < 4; ++v)
    bv[v] = *reinterpret_cast<const short8*>(base + (size_t)(jw + v * 16 + n15) * 64 + 32 + quad * 8);
  float ls[4] = {0.f, 0.f, 0.f, 0.f};
  const unsigned short* ap = base + (size_t)(iz * 256 + n15) * 64 + quad * 8;
  short8 ac = *reinterpret_cast<const short8*>(ap);
  for (int st = 0; st < 16; ++st) {
    short8 an = *reinterpret_cast<const short8*>(ap + (size_t)((st < 15) ? st + 1 : st) * 1024);
#pragma unroll
    for (int v = 0; v < 4; ++v) {
      floatx4 z = {0.f, 0.f, 0.f, 0.f};
      z = __builtin_amdgcn_mfma_f32_16x16x32_bf16(ac, bv[v], z, 0, 0, 0);
      ls[v] += (__builtin_amdgcn_exp2f(z[0]) + __builtin_amdgcn_exp2f(z[1]))
             + (__builtin_amdgcn_exp2f(z[2]) + __builtin_amdgcn_exp2f(z[3]));
    }
    ac = an;
  }
#pragma unroll
  for (int v = 0; v < 4; ++v) {
    ls[v] += __shfl_xor(ls[v], 16);
    ls[v] += __shfl_xor(ls[v], 32);
  }
  if (quad == 0) {
#pragma unroll
    for (int v = 0; v < 4; ++v)
      lpart[((size_t)iz * B_ + b) * N_ + jw + v * 16 + n15] = ls[v];
  }
}

// ---------------- fold softmax denom into g: g[c][j] *= 1/l_j (in place) ----------------
__global__ void __launch_bounds__(256) scale_g_k(
    const float* __restrict__ lpart, unsigned short* __restrict__ g16)
{
  const int b = blockIdx.y;
  const int c0 = blockIdx.z * 8;
  const int j = blockIdx.x * 256 + threadIdx.x;
  float l = 0.f;
#pragma unroll
  for (int iz = 0; iz < 16; ++iz) l += lpart[((size_t)iz * B_ + b) * N_ + j];
  const float rl = 1.f / l;
  unsigned short* gp = g16 + ((size_t)b * 32 + c0) * N_ + j;
#pragma unroll
  for (int c = 0; c < 8; ++c) {
    gp[(size_t)c * N_] = f2bf(bf2f(gp[(size_t)c * N_]) * rl);
  }
}

// ---------------- pass B: GEMM-style with block LDS staging -------------------------
#define PHI_PITCH 40   // 32 elem + 8 pad
#define G_PITCH   136  // 128 elem + 8 pad
__global__ void __launch_bounds__(256, 4) attn_pv_k(
    const unsigned short* __restrict__ thph, const unsigned short* __restrict__ g16,
    unsigned short* __restrict__ y2p)
{
  const int b  = blockIdx.y;
  const int jq = blockIdx.z;
  const int t = threadIdx.x, wave = t >> 6, lane = t & 63;
  const int n15 = lane & 15, quad = lane >> 4;
  const int iw = blockIdx.x * 64 + wave * 16;
  const unsigned short* base = thph + (size_t)b * N_ * 64;
  const unsigned short* gs   = g16  + (size_t)b * 32 * N_;
  __shared__ unsigned short phi_lds[2][128 * PHI_PITCH];
  __shared__ unsigned short g_lds[2][32 * G_PITCH];

  const short8 bth = *reinterpret_cast<const short8*>(base + (size_t)(iw + n15) * 64 + quad * 8);
  floatx4 Y0 = {0.f, 0.f, 0.f, 0.f}, Y1 = {0.f, 0.f, 0.f, 0.f};

  const int rphi = wave * 32 + (lane >> 2), cph = lane & 3;
  const int cg   = wave * 8  + (lane >> 4), chg = lane & 15;

  uint4 sp0, sp1, sg0, sg1;
  const int jbase = jq * 1024;
  sp0 = *reinterpret_cast<const uint4*>(base + (size_t)(jbase + rphi) * 64 + 32 + cph * 8);
  sp1 = *reinterpret_cast<const uint4*>(base + (size_t)(jbase + rphi + 16) * 64 + 32 + cph * 8);
  sg0 = *reinterpret_cast<const uint4*>(gs + (size_t)cg * N_ + jbase + chg * 8);
  sg1 = *reinterpret_cast<const uint4*>(gs + (size_t)(cg + 4) * N_ + jbase + chg * 8);
  *reinterpret_cast<uint4*>(&phi_lds[0][rphi * PHI_PITCH + cph * 8]) = sp0;
  *reinterpret_cast<uint4*>(&phi_lds[0][(rphi + 16) * PHI_PITCH + cph * 8]) = sp1;
  *reinterpret_cast<uint4*>(&g_lds[0][cg * G_PITCH + chg * 8]) = sg0;
  *reinterpret_cast<uint4*>(&g_lds[0][(cg + 4) * G_PITCH + chg * 8]) = sg1;
  __syncthreads();

  int j0 = jbase;
  for (int ch = 0; ch < 8; ++ch, j0 += 128) {
    const int cur = ch & 1;
    if (ch < 7) {
      const int jn = j0 + 128;
      sp0 = *reinterpret_cast<const uint4*>(base + (size_t)(jn + rphi) * 64 + 32 + cph * 8);
      sp1 = *reinterpret_cast<const uint4*>(base + (size_t)(jn + rphi + 16) * 64 + 32 + cph * 8);
      sg0 = *reinterpret_cast<const uint4*>(gs + (size_t)cg * N_ + jn + chg * 8);
      sg1 = *reinterpret_cast<const uint4*>(gs + (size_t)(cg + 4) * N_ + jn + chg * 8);
    }
    const unsigned short* phb = &phi_lds[cur][0];
    const unsigned short* glb = &g_lds[cur][0];
    unsigned pk[8][2];
#pragma unroll
    for (int jt = 0; jt < 8; ++jt) {
      short8 aph = *reinterpret_cast<const short8*>(phb + (jt * 16 + n15) * PHI_PITCH + quad * 8);
      floatx4 z = {0.f, 0.f, 0.f, 0.f};
      z = __builtin_amdgcn_mfma_f32_16x16x32_bf16(aph, bth, z, 0, 0, 0);
      float e0 = __builtin_amdgcn_exp2f(z[0]), e1 = __builtin_amdgcn_exp2f(z[1]);
      float e2 = __builtin_amdgcn_exp2f(z[2]), e3 = __builtin_amdgcn_exp2f(z[3]);
      pk[jt][0] = __builtin_amdgcn_perm(__float_as_uint(e1), __float_as_uint(e0), 0x07060302);
      pk[jt][1] = __builtin_amdgcn_perm(__float_as_uint(e3), __float_as_uint(e2), 0x07060302);
    }
#pragma unroll
    for (int sg = 0; sg < 4; ++sg) {
      union { unsigned u[4]; short8 v; } pa, gb0, gb1;
      pa.u[0] = pk[2 * sg][0];     pa.u[1] = pk[2 * sg][1];
      pa.u[2] = pk[2 * sg + 1][0]; pa.u[3] = pk[2 * sg + 1][1];
      const unsigned short* gr0 = glb + n15 * G_PITCH + sg * 32 + quad * 4;
      const unsigned short* gr1 = glb + (16 + n15) * G_PITCH + sg * 32 + quad * 4;
      uint2 lo0 = *reinterpret_cast<const uint2*>(gr0);
      uint2 hi0 = *reinterpret_cast<const uint2*>(gr0 + 16);
      uint2 lo1 = *reinterpret_cast<const uint2*>(gr1);
      uint2 hi1 = *reinterpret_cast<const uint2*>(gr1 + 16);
      gb0.u[0] = lo0.x; gb0.u[1] = lo0.y; gb0.u[2] = hi0.x; gb0.u[3] = hi0.y;
      gb1.u[0] = lo1.x; gb1.u[1] = lo1.y; gb1.u[2] = hi1.x; gb1.u[3] = hi1.y;
      Y0 = __builtin_amdgcn_mfma_f32_16x16x32_bf16(pa.v, gb0.v, Y0, 0, 0, 0);
      Y1 = __builtin_amdgcn_mfma_f32_16x16x32_bf16(pa.v, gb1.v, Y1, 0, 0, 0);
    }
    if (ch < 7) {
      const int nb = cur ^ 1;
      *reinterpret_cast<uint4*>(&phi_lds[nb][rphi * PHI_PITCH + cph * 8]) = sp0;
      *reinterpret_cast<uint4*>(&phi_lds[nb][(rphi + 16) * PHI_PITCH + cph * 8]) = sp1;
      *reinterpret_cast<uint4*>(&g_lds[nb][cg * G_PITCH + chg * 8]) = sg0;
      *reinterpret_cast<uint4*>(&g_lds[nb][(cg + 4) * G_PITCH + chg * 8]) = sg1;
    }
    __syncthreads();
  }
  unsigned w0[2], w1[2];
  w0[0] = ((unsigned)f2bf(Y0[1]) << 16) | f2bf(Y0[0]);
  w0[1] = ((unsigned)f2bf(Y0[3]) << 16) | f2bf(Y0[2]);
  w1[0] = ((unsigned)f2bf(Y1[1]) << 16) | f2bf(Y1[0]);
  w1[1] = ((unsigned)f2bf(Y1[3]) << 16) | f2bf(Y1[2]);
  *reinterpret_cast<uint2*>(
      y2p + (((size_t)jq * B_ + b) * 32 + n15) * N_ + iw + quad * 4) =
      *reinterpret_cast<uint2*>(w0);
  *reinterpret_cast<uint2*>(
      y2p + (((size_t)jq * B_ + b) * 32 + 16 + n15) * N_ + iw + quad * 4) =
      *reinterpret_cast<uint2*>(w1);
}

// ---------------- final: out = (W_y(y2) + am) * x ----------------
__global__ void __launch_bounds__(256) final_k(
    const unsigned short* __restrict__ y2p, const float* __restrict__ w_w,
    const float* __restrict__ w_b, const unsigned short* __restrict__ am_cl,
    const float* __restrict__ x, float* __restrict__ out)
{
  const int n0 = (blockIdx.x * 256 + threadIdx.x) * 2;
  const int o0 = blockIdx.y * 8;
  const int b  = blockIdx.z;
  float a0[8], a1[8];
#pragma unroll
  for (int u = 0; u < 8; ++u) { a0[u] = w_b[o0 + u]; a1[u] = a0[u]; }
  for (int c = 0; c < 32; ++c) {
    float s0 = 0.f, s1 = 0.f;
#pragma unroll
    for (int ph = 0; ph < 4; ++ph) {
      unsigned v = *reinterpret_cast<const unsigned*>(
          y2p + (((size_t)ph * B_ + b) * 32 + c) * N_ + n0);
      s0 += bf2f((unsigned short)(v & 0xffffu));
      s1 += bf2f((unsigned short)(v >> 16));
    }
#pragma unroll
    for (int u = 0; u < 8; ++u) {
      float wv = w_w[(o0 + u) * 32 + c];
      a0[u] += wv * s0; a1[u] += wv * s1;
    }
  }
  const short8 am0 = *reinterpret_cast<const short8*>(am_cl + ((size_t)b * N_ + n0) * 64 + o0);
  const short8 am1 = *reinterpret_cast<const short8*>(am_cl + ((size_t)b * N_ + n0 + 1) * 64 + o0);
#pragma unroll
  for (int u = 0; u < 8; ++u) {
    size_t off = ((size_t)b * 64 + o0 + u) * N_ + n0;
    float2 xv = *reinterpret_cast<const float2*>(x + off);
    float2 ov;
    ov.x = (a0[u] + bf2f((unsigned short)am0[u])) * xv.x;
    ov.y = (a1[u] + bf2f((unsigned short)am1[u])) * xv.y;
    *reinterpret_cast<float2*>(out + off) = ov;
  }
}

extern "C" void kernel_launch(void* const* d_in, const int* in_sizes, int n_in,
                              void* d_out, int out_size, void* d_ws, size_t ws_size,
                              hipStream_t stream) {
  const float* x    = (const float*)d_in[0];
  const float* d1_w = (const float*)d_in[1];
  const float* d1_b = (const float*)d_in[2];
  const float* d2_w = (const float*)d_in[3];
  const float* d2_b = (const float*)d_in[4];
  const float* d3_w = (const float*)d_in[5];
  const float* d3_b = (const float*)d_in[6];
  const float* g_w  = (const float*)d_in[7];
  const float* g_b  = (const float*)d_in[8];
  const float* th_w = (const float*)d_in[9];
  const float* th_b = (const float*)d_in[10];
  const float* ph_w = (const float*)d_in[11];
  const float* ph_b = (const float*)d_in[12];
  const float* w_w  = (const float*)d_in[13];
  const float* w_b  = (const float*)d_in[14];
  float* out = (float*)d_out;

  char* p = (char*)d_ws;
  unsigned short* am_cl = (unsigned short*)p;  p += (size_t)B_ * N_ * 64 * 2;        // 2 MB
  unsigned short* thph  = (unsigned short*)p;  p += (size_t)B_ * N_ * 64 * 2;        // 2 MB
  unsigned short* g16   = (unsigned short*)p;  p += (size_t)B_ * 32 * N_ * 2;        // 1 MB
  float* lpart          = (float*)p;           p += (size_t)16 * B_ * N_ * 4;        // 1 MB
  unsigned short* y2p   = (unsigned short*)p;  p += (size_t)4 * B_ * 32 * N_ * 2;    // 4 MB
  float* y3cl           = (float*)p;           p += (size_t)B_ * 64 * 64 * 4;        // 64 KB
  unsigned short* wpk   = (unsigned short*)p;  p += (size_t)3 * 36864 * 2;
  unsigned short* wproj = (unsigned short*)p;  p += (size_t)96 * 64 * 2;
  float* bproj          = (float*)p;           p += (size_t)96 * 4;
  char* zbase = p;
  unsigned short* xclp  = (unsigned short*)p;  p += (size_t)B_ * 66 * 66 * 64 * 2;
  unsigned short* y1clp = (unsigned short*)p;  p += (size_t)B_ * 34 * 34 * 64 * 2;
  unsigned short* y2clp = (unsigned short*)p;  p += (size_t)B_ * 18 * 18 * 64 * 2;
  const size_t zbytes = (size_t)(p - zbase);

  hipMemsetAsync(zbase, 0, zbytes, stream);
  pack_xw_k<<<272, 256, 0, stream>>>(x, xclp, d1_w, d2_w, d3_w, th_w, ph_w, g_w,
                                     th_b, ph_b, g_b, wpk, wproj, bproj);
  convmf_k<66, 32, true,  true ><<<1024, 64, 0, stream>>>(xclp,  wpk,             d1_b, y1clp, nullptr);
  convmf_k<34, 16, true,  true ><<<256,  64, 0, stream>>>(y1clp, wpk + 36864,     d2_b, y2clp, nullptr);
  convmf_k<18,  8, false, false><<<64,   64, 0, stream>>>(y2clp, wpk + 2 * 36864, d3_b, nullptr, y3cl);
  upsproj_k<<<256, 256, 0, stream>>>(y3cl, x, wproj, bproj, am_cl, thph, g16);
  attn_stats_k<<<dim3(16, 4, 16), 256, 0, stream>>>(thph, lpart);
  scale_g_k<<<dim3(16, 4, 4), 256, 0, stream>>>(lpart, g16);
  attn_pv_k<<<dim3(64, 4, 4), 256, 0, stream>>>(thph, g16, y2p);
  final_k<<<dim3(8, 8, 4), 256, 0, stream>>>(y2p, w_w, w_b, am_cl, x, out);
}